// Round 8
// baseline (1818.770 us; speedup 1.0000x reference)
//
#include <hip/hip_runtime.h>

// ---------------------------------------------------------------------------
// Encoder_Decoder: 80-class bidirectional GRU encoder (H=128) + GRU decoder
// (DH=256) with teacher forcing, plus two shared dense layers.
// v8: decoder stops fighting the immovable 84-VGPR budget (6 rounds, 6
// structures, VGPR_Count=84 every time). The 970us loop is BW-bound on the
// compiler's fp32 scratch stream (786KB/block/step @ ~180B/cy). Replace it
// with an EXPLICIT f16 weight stream: one-time pack of dec_Whh into a
// lane-coalesced f16x2 layout (reusing the dead allf region), consumed by an
// 8-slot rolling dwordx4 prefetch pipeline (stable slot<->chunk map mod 32,
// 8KB/wave in flight). Halves streamed bytes, fits 84 regs (no spill), and
// raw s_barrier + lgkmcnt(0) keeps prefetches alive across barriers.
// ---------------------------------------------------------------------------

typedef __fp16 h2v __attribute__((ext_vector_type(2)));
typedef __fp16 h8 __attribute__((ext_vector_type(8)));

__device__ __forceinline__ h2v pk2(float a, float b) {
  return __builtin_amdgcn_cvt_pkrtz(a, b);
}
__device__ __forceinline__ unsigned h2u(h2v h) { return __builtin_bit_cast(unsigned, h); }
__device__ __forceinline__ h2v u2h(unsigned u) { return __builtin_bit_cast(h2v, u); }
__device__ __forceinline__ float fdot2f(h2v a, h2v b, float c) {
  return __builtin_amdgcn_fdot2(a, b, c, false);
}
__device__ __forceinline__ float sigf(float x) { return 1.f / (1.f + __expf(-x)); }
__device__ __forceinline__ float tanhfast(float x) { return 2.f / (1.f + __expf(-2.f * x)) - 1.f; }

__device__ __forceinline__ h8 pack8(float4 a, float4 b) {
  h2v p0 = pk2(a.x, a.y), p1 = pk2(a.z, a.w), p2 = pk2(b.x, b.y), p3 = pk2(b.z, b.w);
  return (h8){p0[0], p0[1], p1[0], p1[1], p2[0], p2[1], p3[0], p3[1]};
}

// constant-index h2v slice of an h8 (subregister alias, no code)
#define SL(V, j) (__builtin_shufflevector((V), (V), 2 * (j), 2 * (j) + 1))

// acc + (partner-lane v) via DPP. CTRL: 0xB1 = quad_perm[1,0,3,2] (xor1),
// 0x4E = quad_perm[2,3,0,1] (xor2), 0x128 = row_ror:8 (xor8 within 16-row).
template <int CTRL>
__device__ __forceinline__ float dppadd(float acc, float v) {
  int r = __builtin_amdgcn_update_dpp(0, __float_as_int(v), CTRL, 0xF, 0xF, true);
  return acc + __int_as_float(r);
}
// xor-4 via ds_swizzle BitMode: (4<<10)|0x1F
__device__ __forceinline__ float swz4add(float acc, float v) {
  return acc + __int_as_float(__builtin_amdgcn_ds_swizzle(__float_as_int(v), 0x101F));
}

// Reduce 8 partials (arg k on lane holds row-id k^(m&7)) across a 16-lane
// group; returns the full sum for row-id (m&7) (identical on lanes m, m^8).
__device__ __forceinline__ float reduce8s(float p0, float p1, float p2, float p3,
                                          float p4, float p5, float p6, float p7) {
  p0 = dppadd<0xB1>(p0, p1);
  p2 = dppadd<0xB1>(p2, p3);
  p4 = dppadd<0xB1>(p4, p5);
  p6 = dppadd<0xB1>(p6, p7);
  p0 = dppadd<0x4E>(p0, p2);
  p4 = dppadd<0x4E>(p4, p6);
  p0 = swz4add(p0, p4);
  p0 = dppadd<0x128>(p0, p0);
  return p0;
}

// 8-col dot: h8 weight slice vs 4 h2v activations
__device__ __forceinline__ float dot4(h8 V, h2v a0, h2v a1, h2v a2, h2v a3, float acc) {
  acc = fdot2f(SL(V, 0), a0, acc);
  acc = fdot2f(SL(V, 1), a1, acc);
  acc = fdot2f(SL(V, 2), a2, acc);
  acc = fdot2f(SL(V, 3), a3, acc);
  return acc;
}

// ---------------------------------------------------------------------------
// K0: fill allf[:,128:224] with score|box|origin_score
// ---------------------------------------------------------------------------
__global__ void k_fill_misc(const float* __restrict__ score, const float* __restrict__ box,
                            const float* __restrict__ orig, float* __restrict__ allf) {
  int i = blockIdx.x * blockDim.x + threadIdx.x;
  if (i >= 40960 * 96) return;
  int row = i / 96, k = i - row * 96;
  float v;
  if (k == 0) v = score[row];
  else if (k < 5) v = box[row * 4 + (k - 1)];
  else v = orig[(size_t)row * 91 + (k - 5)];
  allf[(size_t)row * 224 + 128 + k] = v;
}

// ---------------------------------------------------------------------------
// K1: allf[:,0:128] = relu(feat @ appear_W^T + appear_b)
// ---------------------------------------------------------------------------
__global__ __launch_bounds__(256) void k_gemm_appear(
    const float* __restrict__ A, const float* __restrict__ W,
    const float* __restrict__ bias, float* __restrict__ allf) {
  __shared__ float As[32][68];
  __shared__ float Ws[32][132];
  const int tid = threadIdx.x;
  const int tx = tid & 15, ty = tid >> 4;
  const int r0 = blockIdx.x * 64;
  const int lr = tid >> 3;
  const int lk = (tid & 7) * 4;
  float acc[4][8];
#pragma unroll
  for (int i = 0; i < 4; ++i)
#pragma unroll
    for (int j = 0; j < 8; ++j) acc[i][j] = 0.f;

  for (int k0 = 0; k0 < 1024; k0 += 32) {
#pragma unroll
    for (int i = 0; i < 2; ++i) {
      int rr = lr + i * 32;
      float4 v = *(const float4*)(A + (size_t)(r0 + rr) * 1024 + k0 + lk);
      As[lk + 0][rr] = v.x; As[lk + 1][rr] = v.y; As[lk + 2][rr] = v.z; As[lk + 3][rr] = v.w;
    }
#pragma unroll
    for (int i = 0; i < 4; ++i) {
      int wr = lr + i * 32;
      float4 v = *(const float4*)(W + (size_t)wr * 1024 + k0 + lk);
      Ws[lk + 0][wr] = v.x; Ws[lk + 1][wr] = v.y; Ws[lk + 2][wr] = v.z; Ws[lk + 3][wr] = v.w;
    }
    __syncthreads();
#pragma unroll
    for (int kk = 0; kk < 32; ++kk) {
      float4 a = *(const float4*)&As[kk][ty * 4];
      float4 w0 = *(const float4*)&Ws[kk][tx * 8];
      float4 w1 = *(const float4*)&Ws[kk][tx * 8 + 4];
      float av[4] = {a.x, a.y, a.z, a.w};
      float wv[8] = {w0.x, w0.y, w0.z, w0.w, w1.x, w1.y, w1.z, w1.w};
#pragma unroll
      for (int i = 0; i < 4; ++i)
#pragma unroll
        for (int j = 0; j < 8; ++j) acc[i][j] = fmaf(av[i], wv[j], acc[i][j]);
    }
    __syncthreads();
  }
#pragma unroll
  for (int i = 0; i < 4; ++i) {
    int row = r0 + ty * 4 + i;
#pragma unroll
    for (int j = 0; j < 8; ++j) {
      int col = tx * 8 + j;
      float v = acc[i][j] + bias[col];
      allf[(size_t)row * 224 + col] = fmaxf(v, 0.f);
    }
  }
}

// ---------------------------------------------------------------------------
// K2: enc_feat = relu(allf @ featlin_W^T + b), stored packed f16x2
// ---------------------------------------------------------------------------
__global__ __launch_bounds__(256) void k_gemm_featlin(
    const float* __restrict__ A, const float* __restrict__ W,
    const float* __restrict__ bias, unsigned* __restrict__ encf2) {
  __shared__ float As[32][68];
  __shared__ float Ws[32][132];
  const int tid = threadIdx.x;
  const int tx = tid & 15, ty = tid >> 4;
  const int r0 = blockIdx.x * 64;
  const int lr = tid >> 3;
  const int lk = (tid & 7) * 4;
  float acc[4][8];
#pragma unroll
  for (int i = 0; i < 4; ++i)
#pragma unroll
    for (int j = 0; j < 8; ++j) acc[i][j] = 0.f;

  for (int k0 = 0; k0 < 224; k0 += 32) {
#pragma unroll
    for (int i = 0; i < 2; ++i) {
      int rr = lr + i * 32;
      float4 v = *(const float4*)(A + (size_t)(r0 + rr) * 224 + k0 + lk);
      As[lk + 0][rr] = v.x; As[lk + 1][rr] = v.y; As[lk + 2][rr] = v.z; As[lk + 3][rr] = v.w;
    }
#pragma unroll
    for (int i = 0; i < 4; ++i) {
      int wr = lr + i * 32;
      float4 v = *(const float4*)(W + (size_t)wr * 224 + k0 + lk);
      Ws[lk + 0][wr] = v.x; Ws[lk + 1][wr] = v.y; Ws[lk + 2][wr] = v.z; Ws[lk + 3][wr] = v.w;
    }
    __syncthreads();
#pragma unroll
    for (int kk = 0; kk < 32; ++kk) {
      float4 a = *(const float4*)&As[kk][ty * 4];
      float4 w0 = *(const float4*)&Ws[kk][tx * 8];
      float4 w1 = *(const float4*)&Ws[kk][tx * 8 + 4];
      float av[4] = {a.x, a.y, a.z, a.w};
      float wv[8] = {w0.x, w0.y, w0.z, w0.w, w1.x, w1.y, w1.z, w1.w};
#pragma unroll
      for (int i = 0; i < 4; ++i)
#pragma unroll
        for (int j = 0; j < 8; ++j) acc[i][j] = fmaf(av[i], wv[j], acc[i][j]);
    }
    __syncthreads();
  }
#pragma unroll
  for (int i = 0; i < 4; ++i) {
    int row = r0 + ty * 4 + i;
    unsigned* orow = encf2 + (size_t)row * 64;
#pragma unroll
    for (int p = 0; p < 4; ++p) {
      int col = tx * 8 + 2 * p;
      float a = fmaxf(acc[i][2 * p] + bias[col], 0.f);
      float b = fmaxf(acc[i][2 * p + 1] + bias[col + 1], 0.f);
      orow[tx * 4 + p] = h2u(pk2(a, b));
    }
  }
}

// ---------------------------------------------------------------------------
// K3: decoder input projections: gi[c][v][r] = dec_Wih[c][r]@dec_emb[v] + bih
// ---------------------------------------------------------------------------
__global__ __launch_bounds__(256) void k_dec_gi(
    const float* __restrict__ Wih, const float* __restrict__ bih,
    const float* __restrict__ emb, float* __restrict__ gi) {
  __shared__ float e[4][32];
  const int c = blockIdx.x, tid = threadIdx.x;
  if (tid < 128) e[tid >> 5][tid & 31] = emb[tid];
  __syncthreads();
#pragma unroll
  for (int i = 0; i < 3; ++i) {
    int r = tid + i * 256;
    const float* w = Wih + ((size_t)c * 768 + r) * 32;
    float b = bih[(size_t)c * 768 + r];
    float a0 = b, a1 = b, a2 = b, a3 = b;
#pragma unroll
    for (int k = 0; k < 32; ++k) {
      float wv = w[k];
      a0 = fmaf(wv, e[0][k], a0);
      a1 = fmaf(wv, e[1][k], a1);
      a2 = fmaf(wv, e[2][k], a2);
      a3 = fmaf(wv, e[3][k], a3);
    }
    gi[((size_t)c * 4 + 0) * 768 + r] = a0;
    gi[((size_t)c * 4 + 1) * 768 + r] = a1;
    gi[((size_t)c * 4 + 2) * 768 + r] = a2;
    gi[((size_t)c * 4 + 3) * 768 + r] = a3;
  }
}

// ---------------------------------------------------------------------------
// K3b: pack dec_Whh (f32) -> f16x2 stream layout wpk[(c*32+ic)*768+tid] uint4.
// Chunk ic (0..31): kc=ic>>4, k=(ic>>1)&7, half=ic&1; thread tid=(w,q,m,mw)
// owns row 64w+16q+8kc+(k^mw), cols [16m+8*half .. +7].
// ---------------------------------------------------------------------------
__global__ __launch_bounds__(768) void k_pack_dec(
    const float* __restrict__ Whh, uint4* __restrict__ wpk) {
  const int c = blockIdx.x >> 5, ic = blockIdx.x & 31;
  const int tid = threadIdx.x;
  const int w = tid >> 6, l = tid & 63, q = l >> 4, m = l & 15, mw = m & 7;
  const int kc = ic >> 4, kk = (ic >> 1) & 7, half = ic & 1;
  const int row = 64 * w + 16 * q + 8 * kc + (kk ^ mw);
  const float* src = Whh + ((size_t)c * 768 + row) * 256 + 16 * m + 8 * half;
  float4 a = *(const float4*)(src);
  float4 b = *(const float4*)(src + 4);
  uint4 o;
  o.x = h2u(pk2(a.x, a.y));
  o.y = h2u(pk2(a.z, a.w));
  o.z = h2u(pk2(b.x, b.y));
  o.w = h2u(pk2(b.z, b.w));
  wpk[((size_t)c * 32 + ic) * 768 + tid] = o;
}

// ---------------------------------------------------------------------------
// K4: per-(class,dir) encoder GRU (unchanged this round, v6 structure).
// ---------------------------------------------------------------------------
#define ENCROW(k)                                                                   \
  h8 ci_##k, ch_##k, sg_##k;                                                        \
  {                                                                                 \
    int vc = 32 * w + 8 * q + ((k) ^ mw);                                           \
    const float4* pi = (const float4*)(Wih + (size_t)vc * 128 + 8 * m);             \
    ci_##k = pack8(pi[0], pi[1]);                                                   \
    __builtin_amdgcn_sched_barrier(0);                                              \
    const float4* ph = (const float4*)(Whh + (size_t)vc * 128 + 8 * m);             \
    ch_##k = pack8(ph[0], ph[1]);                                                   \
    __builtin_amdgcn_sched_barrier(0);                                              \
    int s = (w < 4) ? vc : (vc - 128);                                              \
    const float* sb =                                                               \
        (w < 4) ? (Wih + (size_t)(256 + s) * 128) : (Whh + (size_t)(256 + s) * 128);\
    const float4* ps = (const float4*)(sb + 8 * m);                                 \
    sg_##k = pack8(ps[0], ps[1]);                                                   \
    __builtin_amdgcn_sched_barrier(0);                                              \
  }

#define EDOTC(k) dot4(ci_##k, x0, x1, x2, x3, dot4(ch_##k, g0, g1, g2, g3, 0.f))
#define EDOTS(k) dot4(sg_##k, s0, s1, s2, s3, 0.f)

__global__ __launch_bounds__(512) void k_enc_gru(
    const unsigned* __restrict__ encf2,
    const float* __restrict__ WihF, const float* __restrict__ WhhF,
    const float* __restrict__ bihF, const float* __restrict__ bhhF,
    const float* __restrict__ WihB, const float* __restrict__ WhhB,
    const float* __restrict__ bihB, const float* __restrict__ bhhB,
    float* __restrict__ dec_h0) {
  const int blk = blockIdx.x;
  const int c = blk >> 1, dir = blk & 1;
  const int tid = threadIdx.x;
  const int w = tid >> 6, l = tid & 63, q = l >> 4, m = l & 15, mw = m & 7;

  const float* Wih = (dir ? WihB : WihF) + (size_t)c * 384 * 128;
  const float* Whh = (dir ? WhhB : WhhF) + (size_t)c * 384 * 128;
  const float* bih = (dir ? bihB : bihF) + (size_t)c * 384;
  const float* bhh = (dir ? bhhB : bhhF) + (size_t)c * 384;

  __shared__ __align__(16) unsigned x2s[2][64];
  __shared__ __align__(16) unsigned h2s[64];
  __shared__ float aBuf[512];

  ENCROW(0) ENCROW(1) ENCROW(2) ENCROW(3)
  ENCROW(4) ENCROW(5) ENCROW(6) ENCROW(7)

  float bown;
  int ownIdx;
  if (m < 8) {
    int vo = 32 * w + 8 * q + m;
    bown = bih[vo] + bhh[vo];
    ownIdx = vo;
  } else {
    int so = (w < 4) ? (32 * w + 8 * q + mw) : (32 * (w - 4) + 8 * q + mw);
    bown = (w < 4) ? bih[256 + so] : bhh[256 + so];
    ownIdx = (w < 4) ? (256 + so) : (384 + so);
  }

  if (tid < 64) h2s[tid] = 0u;
  if (tid >= 448) {
    int lane = tid - 448;
    x2s[0][lane] = (dir == 0) ? encf2[((size_t)c * 512 + 0) * 64 + lane] : 0x3C003C00u;
  }
  float hreg = 0.f;
  __syncthreads();

  for (int t = 0; t <= 512; ++t) {
    unsigned xpre = 0;
    if (tid >= 448 && t < 512) {  // issue next-x load early; hides under matvec
      int tn = t + 1, lane = tid - 448;
      int row = (dir == 0) ? ((tn < 512) ? tn : -1) : (512 - tn);
      xpre = (row < 0) ? 0x3C003C00u : encf2[((size_t)c * 512 + row) * 64 + lane];
    }
    uint4 xv = ((const uint4*)&x2s[t & 1][0])[m];
    uint4 hv = ((const uint4*)&h2s[0])[m];
    h2v x0 = u2h(xv.x), x1 = u2h(xv.y), x2 = u2h(xv.z), x3 = u2h(xv.w);
    h2v g0 = u2h(hv.x), g1 = u2h(hv.y), g2 = u2h(hv.z), g3 = u2h(hv.w);
    float pA = reduce8s(EDOTC(0), EDOTC(1), EDOTC(2), EDOTC(3),
                        EDOTC(4), EDOTC(5), EDOTC(6), EDOTC(7));
    h2v s0 = (w < 4) ? x0 : g0, s1 = (w < 4) ? x1 : g1;
    h2v s2 = (w < 4) ? x2 : g2, s3 = (w < 4) ? x3 : g3;
    float pB = reduce8s(EDOTS(0), EDOTS(1), EDOTS(2), EDOTS(3),
                        EDOTS(4), EDOTS(5), EDOTS(6), EDOTS(7));
    aBuf[ownIdx] = ((m < 8) ? pA : pB) + bown;
    __syncthreads();
    if (tid < 128) {
      float r = sigf(aBuf[tid]);
      float z = sigf(aBuf[128 + tid]);
      float nn = tanhfast(aBuf[256 + tid] + r * aBuf[384 + tid]);
      float hn = (1.f - z) * nn + z * hreg;
      hreg = hn;
      float other = __shfl_xor(hn, 1, 64);
      if ((tid & 1) == 0) h2s[tid >> 1] = h2u(pk2(hn, other));
    } else if (tid >= 448 && t < 512) {
      x2s[(t + 1) & 1][tid - 448] = xpre;
    }
    __syncthreads();
  }
  if (tid < 128) dec_h0[(size_t)c * 256 + dir * 128 + tid] = hreg;
}

// ---------------------------------------------------------------------------
// K5: per-class decoder GRU + fused out-projection + log_softmax.
// 80 blocks x 768 threads. Weights streamed from the f16 packed buffer via an
// 8-slot rolling dwordx4 prefetch pipeline (chunk ic advances mod 32 so the
// slot<->chunk map is stable across steps). Raw s_barrier + lgkmcnt(0) only
// (no vmcnt drain) so prefetches stay in flight across barriers.
// ---------------------------------------------------------------------------
#define CONS(sa, sb, dst)                                   \
  {                                                         \
    float a_ = 0.f;                                         \
    a_ = fdot2f(u2h((sa).x), g0, a_);                       \
    a_ = fdot2f(u2h((sa).y), g1, a_);                       \
    a_ = fdot2f(u2h((sa).z), g2, a_);                       \
    a_ = fdot2f(u2h((sa).w), g3, a_);                       \
    a_ = fdot2f(u2h((sb).x), g4, a_);                       \
    a_ = fdot2f(u2h((sb).y), g5, a_);                       \
    a_ = fdot2f(u2h((sb).z), g6, a_);                       \
    a_ = fdot2f(u2h((sb).w), g7, a_);                       \
    dst = a_;                                               \
  }

#define DITER(P, J, D)                                      \
  CONS(bA##P, bB##P, D);                                    \
  bA##P = wp[((2 * (J) + 8) & 31) * 768];                   \
  bB##P = wp[((2 * (J) + 9) & 31) * 768];

#define BAR_LGKM()                                          \
  asm volatile("s_waitcnt lgkmcnt(0)" ::: "memory");        \
  __builtin_amdgcn_s_barrier();                             \
  asm volatile("" ::: "memory");

__global__ __launch_bounds__(768) void k_dec_gru(
    const uint4* __restrict__ wpk, const float* __restrict__ bhh,
    const float* __restrict__ gi, const float* __restrict__ h0,
    const int* __restrict__ labels,
    const float* __restrict__ outW, const float* __restrict__ outB,
    float* __restrict__ out) {
  const int c = blockIdx.x, tid = threadIdx.x;
  const int w = tid >> 6, l = tid & 63, m = l & 15;

  __shared__ __align__(16) unsigned h2s[128];
  __shared__ float aBuf[768];
  __shared__ float gisf[2304];
  __shared__ float owsh[1024];
  __shared__ int labs[513];
  __shared__ float red[4][4];

  const uint4* wp = wpk + (size_t)c * 32 * 768 + tid;
  // rolling buffer preload: chunks 0..7
  uint4 bA0 = wp[0 * 768], bB0 = wp[1 * 768];
  uint4 bA1 = wp[2 * 768], bB1 = wp[3 * 768];
  uint4 bA2 = wp[4 * 768], bB2 = wp[5 * 768];
  uint4 bA3 = wp[6 * 768], bB3 = wp[7 * 768];

  float bown = bhh[(size_t)c * 768 + 64 * w + l];
  for (int i = tid; i < 2304; i += 768) gisf[i] = gi[(size_t)c * 4 * 768 + i];
  for (int i = tid; i < 1024; i += 768) owsh[i] = outW[i];
  if (tid < 512) labs[tid + 1] = labels[(size_t)c * 512 + tid];
  if (tid == 512) labs[0] = 2;  // SOS
  float b0 = outB[0], b1 = outB[1], b2 = outB[2], b3 = outB[3];
  float hreg = 0.f;
  if (tid < 256) {
    hreg = h0[(size_t)c * 256 + tid];
    float other = __shfl_xor(hreg, 1, 64);
    if ((tid & 1) == 0) h2s[tid >> 1] = h2u(pk2(hreg, other));
  }
  __syncthreads();

  for (int t = 0; t <= 512; ++t) {
    const uint4* hp = (const uint4*)(&h2s[0]);
    uint4 ha = hp[2 * m], hb = hp[2 * m + 1];
    h2v g0 = u2h(ha.x), g1 = u2h(ha.y), g2 = u2h(ha.z), g3 = u2h(ha.w);
    h2v g4 = u2h(hb.x), g5 = u2h(hb.y), g6 = u2h(hb.z), g7 = u2h(hb.w);
    float s0, s1, s2, s3, s4, s5, s6, s7;
    DITER(0, 0, s0) DITER(1, 1, s1) DITER(2, 2, s2) DITER(3, 3, s3)
    DITER(0, 4, s4) DITER(1, 5, s5) DITER(2, 6, s6) DITER(3, 7, s7)
    float pc0 = reduce8s(s0, s1, s2, s3, s4, s5, s6, s7);
    DITER(0, 8, s0) DITER(1, 9, s1) DITER(2, 10, s2) DITER(3, 11, s3)
    DITER(0, 12, s4) DITER(1, 13, s5) DITER(2, 14, s6) DITER(3, 15, s7)
    float pc1 = reduce8s(s0, s1, s2, s3, s4, s5, s6, s7);
    aBuf[64 * w + l] = ((m < 8) ? pc0 : pc1) + bown;
    BAR_LGKM();
    if (tid < 256) {
      int sel = labs[t];
      const float* gsel = &gisf[sel * 768];
      float r = sigf(gsel[tid] + aBuf[tid]);
      float z = sigf(gsel[256 + tid] + aBuf[256 + tid]);
      float nn = tanhfast(gsel[512 + tid] + r * aBuf[512 + tid]);
      float hn = (1.f - z) * nn + z * hreg;
      hreg = hn;
      float other = __shfl_xor(hn, 1, 64);
      if ((tid & 1) == 0) h2s[tid >> 1] = h2u(pk2(hn, other));
      float p0 = owsh[tid] * hn, p1 = owsh[256 + tid] * hn;
      float p2 = owsh[512 + tid] * hn, p3 = owsh[768 + tid] * hn;
#pragma unroll
      for (int off = 32; off > 0; off >>= 1) {
        p0 += __shfl_xor(p0, off, 64);
        p1 += __shfl_xor(p1, off, 64);
        p2 += __shfl_xor(p2, off, 64);
        p3 += __shfl_xor(p3, off, 64);
      }
      if ((tid & 63) == 0) {
        int ww = tid >> 6;
        red[ww][0] = p0; red[ww][1] = p1; red[ww][2] = p2; red[ww][3] = p3;
      }
    }
    BAR_LGKM();
    if (tid == 0) {
      float l0 = red[0][0] + red[1][0] + red[2][0] + red[3][0] + b0;
      float l1 = red[0][1] + red[1][1] + red[2][1] + red[3][1] + b1;
      float l2 = red[0][2] + red[1][2] + red[2][2] + red[3][2] + b2;
      float l3 = red[0][3] + red[1][3] + red[2][3] + red[3][3] + b3;
      float mm = fmaxf(fmaxf(l0, l1), fmaxf(l2, l3));
      float s = __expf(l0 - mm) + __expf(l1 - mm) + __expf(l2 - mm) + __expf(l3 - mm);
      float lse = mm + __logf(s);
      float* o = out + ((size_t)c * 513 + t) * 4;
      o[0] = l0 - lse; o[1] = l1 - lse; o[2] = l2 - lse; o[3] = l3 - lse;
    }
  }
}

// ---------------------------------------------------------------------------
// K6: labels (as float) and weights passthrough
// ---------------------------------------------------------------------------
__global__ void k_passthrough(const int* __restrict__ labels,
                              const float* __restrict__ weights,
                              float* __restrict__ out) {
  int i = blockIdx.x * blockDim.x + threadIdx.x;
  if (i < 40960) {
    out[164160 + i] = (float)labels[i];
    out[164160 + 40960 + i] = weights[i];
  }
}

// ---------------------------------------------------------------------------
extern "C" void kernel_launch(void* const* d_in, const int* in_sizes, int n_in,
                              void* d_out, int out_size, void* d_ws, size_t ws_size,
                              hipStream_t stream) {
  (void)in_sizes; (void)n_in; (void)out_size; (void)ws_size;
  const float* feat = (const float*)d_in[0];
  const float* score = (const float*)d_in[1];
  const float* box = (const float*)d_in[2];
  const float* orig = (const float*)d_in[3];
  const int* labels = (const int*)d_in[4];
  const float* weights = (const float*)d_in[5];
  const float* appear_W = (const float*)d_in[8];
  const float* appear_b = (const float*)d_in[9];
  const float* featlin_W = (const float*)d_in[10];
  const float* featlin_b = (const float*)d_in[11];
  const float* eWihF = (const float*)d_in[12];
  const float* eWhhF = (const float*)d_in[13];
  const float* ebihF = (const float*)d_in[14];
  const float* ebhhF = (const float*)d_in[15];
  const float* eWihB = (const float*)d_in[16];
  const float* eWhhB = (const float*)d_in[17];
  const float* ebihB = (const float*)d_in[18];
  const float* ebhhB = (const float*)d_in[19];
  const float* dec_emb = (const float*)d_in[20];
  const float* dWih = (const float*)d_in[21];
  const float* dWhh = (const float*)d_in[22];
  const float* dbih = (const float*)d_in[23];
  const float* dbhh = (const float*)d_in[24];
  const float* outW = (const float*)d_in[25];
  const float* outB = (const float*)d_in[26];
  float* out = (float*)d_out;

  char* ws = (char*)d_ws;
  float* allf = (float*)ws;                                     // 40960*224 f32 (36.7MB)
  unsigned* encf2 = (unsigned*)(ws + (size_t)40960 * 224 * 4);  // 40960*64 u32
  float* dec_h0 = (float*)(ws + (size_t)40960 * 224 * 4 + (size_t)40960 * 64 * 4);
  float* dec_gi = dec_h0 + 80 * 256;                            // 80*4*768 f32
  // after k_gemm_featlin, allf is dead -> reuse it for the packed f16 weights
  uint4* wpack = (uint4*)allf;                                  // 80*32*768*16B = 31.5MB

  k_fill_misc<<<15360, 256, 0, stream>>>(score, box, orig, allf);
  k_gemm_appear<<<640, 256, 0, stream>>>(feat, appear_W, appear_b, allf);
  k_gemm_featlin<<<640, 256, 0, stream>>>(allf, featlin_W, featlin_b, encf2);
  k_pack_dec<<<80 * 32, 768, 0, stream>>>(dWhh, wpack);
  k_dec_gi<<<80, 256, 0, stream>>>(dWih, dbih, dec_emb, dec_gi);
  k_enc_gru<<<160, 512, 0, stream>>>(encf2, eWihF, eWhhF, ebihF, ebhhF,
                                     eWihB, eWhhB, ebihB, ebhhB, dec_h0);
  k_dec_gru<<<80, 768, 0, stream>>>(wpack, dbhh, dec_gi, dec_h0, labels, outW, outB, out);
  k_passthrough<<<160, 256, 0, stream>>>(labels, weights, out);
}

// Round 9
// 1696.501 us; speedup vs baseline: 1.0721x; 1.0721x over previous
//
#include <hip/hip_runtime.h>

// ---------------------------------------------------------------------------
// Encoder_Decoder v9: three-pipe weight delivery for the GRU loops.
// Evidence to date: the 768x256 (dec) / 384x256 (enc) per-step weight read
// cannot be register-resident (backend pins a ~84-VGPR budget; 6 structural
// attempts), and a single VMEM stream caps at ~86 B/cy/CU (v8). So split:
//   registers (free) + LDS-resident (separate ~128 B/cy pipe, loaded ONCE)
//   + small VMEM stream (under the per-CU return-path wall), with a
//   phase-interleaved 4-slot schedule whose every load has >=600cy lead.
// Decoder: 12 reg chunks / 12 LDS chunks (147KB) / 8 streamed.
// Encoder: 13 reg chunks / 11 LDS chunks (90KB) / 0 streamed.
// ---------------------------------------------------------------------------

typedef __fp16 h2v __attribute__((ext_vector_type(2)));

__device__ __forceinline__ h2v pk2(float a, float b) {
  return __builtin_amdgcn_cvt_pkrtz(a, b);
}
__device__ __forceinline__ unsigned h2u(h2v h) { return __builtin_bit_cast(unsigned, h); }
__device__ __forceinline__ h2v u2h(unsigned u) { return __builtin_bit_cast(h2v, u); }
__device__ __forceinline__ float fdot2f(h2v a, h2v b, float c) {
  return __builtin_amdgcn_fdot2(a, b, c, false);
}
__device__ __forceinline__ float sigf(float x) { return 1.f / (1.f + __expf(-x)); }
__device__ __forceinline__ float tanhfast(float x) { return 2.f / (1.f + __expf(-2.f * x)) - 1.f; }

__device__ __forceinline__ uint4 pack8u(float4 a, float4 b) {
  uint4 o;
  o.x = h2u(pk2(a.x, a.y)); o.y = h2u(pk2(a.z, a.w));
  o.z = h2u(pk2(b.x, b.y)); o.w = h2u(pk2(b.z, b.w));
  return o;
}

// 8-col dot: uint4 of 8 packed f16 weights vs 4 h2v activations
__device__ __forceinline__ float dotu4(uint4 cv, h2v a0, h2v a1, h2v a2, h2v a3,
                                       float acc) {
  acc = fdot2f(u2h(cv.x), a0, acc);
  acc = fdot2f(u2h(cv.y), a1, acc);
  acc = fdot2f(u2h(cv.z), a2, acc);
  acc = fdot2f(u2h(cv.w), a3, acc);
  return acc;
}

// acc + (partner-lane v) via DPP. CTRL: 0xB1 = quad_perm[1,0,3,2] (xor1),
// 0x4E = quad_perm[2,3,0,1] (xor2), 0x128 = row_ror:8.
template <int CTRL>
__device__ __forceinline__ float dppadd(float acc, float v) {
  int r = __builtin_amdgcn_update_dpp(0, __float_as_int(v), CTRL, 0xF, 0xF, true);
  return acc + __int_as_float(r);
}
// xor-4 via ds_swizzle BitMode
__device__ __forceinline__ float swz4add(float acc, float v) {
  return acc + __int_as_float(__builtin_amdgcn_ds_swizzle(__float_as_int(v), 0x101F));
}

// ---------------------------------------------------------------------------
// K0: fill allf[:,128:224]
// ---------------------------------------------------------------------------
__global__ void k_fill_misc(const float* __restrict__ score, const float* __restrict__ box,
                            const float* __restrict__ orig, float* __restrict__ allf) {
  int i = blockIdx.x * blockDim.x + threadIdx.x;
  if (i >= 40960 * 96) return;
  int row = i / 96, k = i - row * 96;
  float v;
  if (k == 0) v = score[row];
  else if (k < 5) v = box[row * 4 + (k - 1)];
  else v = orig[(size_t)row * 91 + (k - 5)];
  allf[(size_t)row * 224 + 128 + k] = v;
}

// ---------------------------------------------------------------------------
// K1: allf[:,0:128] = relu(feat @ appear_W^T + appear_b)
// ---------------------------------------------------------------------------
__global__ __launch_bounds__(256) void k_gemm_appear(
    const float* __restrict__ A, const float* __restrict__ W,
    const float* __restrict__ bias, float* __restrict__ allf) {
  __shared__ float As[32][68];
  __shared__ float Ws[32][132];
  const int tid = threadIdx.x;
  const int tx = tid & 15, ty = tid >> 4;
  const int r0 = blockIdx.x * 64;
  const int lr = tid >> 3;
  const int lk = (tid & 7) * 4;
  float acc[4][8];
#pragma unroll
  for (int i = 0; i < 4; ++i)
#pragma unroll
    for (int j = 0; j < 8; ++j) acc[i][j] = 0.f;

  for (int k0 = 0; k0 < 1024; k0 += 32) {
#pragma unroll
    for (int i = 0; i < 2; ++i) {
      int rr = lr + i * 32;
      float4 v = *(const float4*)(A + (size_t)(r0 + rr) * 1024 + k0 + lk);
      As[lk + 0][rr] = v.x; As[lk + 1][rr] = v.y; As[lk + 2][rr] = v.z; As[lk + 3][rr] = v.w;
    }
#pragma unroll
    for (int i = 0; i < 4; ++i) {
      int wr = lr + i * 32;
      float4 v = *(const float4*)(W + (size_t)wr * 1024 + k0 + lk);
      Ws[lk + 0][wr] = v.x; Ws[lk + 1][wr] = v.y; Ws[lk + 2][wr] = v.z; Ws[lk + 3][wr] = v.w;
    }
    __syncthreads();
#pragma unroll
    for (int kk = 0; kk < 32; ++kk) {
      float4 a = *(const float4*)&As[kk][ty * 4];
      float4 w0 = *(const float4*)&Ws[kk][tx * 8];
      float4 w1 = *(const float4*)&Ws[kk][tx * 8 + 4];
      float av[4] = {a.x, a.y, a.z, a.w};
      float wv[8] = {w0.x, w0.y, w0.z, w0.w, w1.x, w1.y, w1.z, w1.w};
#pragma unroll
      for (int i = 0; i < 4; ++i)
#pragma unroll
        for (int j = 0; j < 8; ++j) acc[i][j] = fmaf(av[i], wv[j], acc[i][j]);
    }
    __syncthreads();
  }
#pragma unroll
  for (int i = 0; i < 4; ++i) {
    int row = r0 + ty * 4 + i;
#pragma unroll
    for (int j = 0; j < 8; ++j) {
      int col = tx * 8 + j;
      float v = acc[i][j] + bias[col];
      allf[(size_t)row * 224 + col] = fmaxf(v, 0.f);
    }
  }
}

// ---------------------------------------------------------------------------
// K2: enc_feat = relu(allf @ featlin_W^T + b), stored packed f16x2
// ---------------------------------------------------------------------------
__global__ __launch_bounds__(256) void k_gemm_featlin(
    const float* __restrict__ A, const float* __restrict__ W,
    const float* __restrict__ bias, unsigned* __restrict__ encf2) {
  __shared__ float As[32][68];
  __shared__ float Ws[32][132];
  const int tid = threadIdx.x;
  const int tx = tid & 15, ty = tid >> 4;
  const int r0 = blockIdx.x * 64;
  const int lr = tid >> 3;
  const int lk = (tid & 7) * 4;
  float acc[4][8];
#pragma unroll
  for (int i = 0; i < 4; ++i)
#pragma unroll
    for (int j = 0; j < 8; ++j) acc[i][j] = 0.f;

  for (int k0 = 0; k0 < 224; k0 += 32) {
#pragma unroll
    for (int i = 0; i < 2; ++i) {
      int rr = lr + i * 32;
      float4 v = *(const float4*)(A + (size_t)(r0 + rr) * 224 + k0 + lk);
      As[lk + 0][rr] = v.x; As[lk + 1][rr] = v.y; As[lk + 2][rr] = v.z; As[lk + 3][rr] = v.w;
    }
#pragma unroll
    for (int i = 0; i < 4; ++i) {
      int wr = lr + i * 32;
      float4 v = *(const float4*)(W + (size_t)wr * 224 + k0 + lk);
      Ws[lk + 0][wr] = v.x; Ws[lk + 1][wr] = v.y; Ws[lk + 2][wr] = v.z; Ws[lk + 3][wr] = v.w;
    }
    __syncthreads();
#pragma unroll
    for (int kk = 0; kk < 32; ++kk) {
      float4 a = *(const float4*)&As[kk][ty * 4];
      float4 w0 = *(const float4*)&Ws[kk][tx * 8];
      float4 w1 = *(const float4*)&Ws[kk][tx * 8 + 4];
      float av[4] = {a.x, a.y, a.z, a.w};
      float wv[8] = {w0.x, w0.y, w0.z, w0.w, w1.x, w1.y, w1.z, w1.w};
#pragma unroll
      for (int i = 0; i < 4; ++i)
#pragma unroll
        for (int j = 0; j < 8; ++j) acc[i][j] = fmaf(av[i], wv[j], acc[i][j]);
    }
    __syncthreads();
  }
#pragma unroll
  for (int i = 0; i < 4; ++i) {
    int row = r0 + ty * 4 + i;
    unsigned* orow = encf2 + (size_t)row * 64;
#pragma unroll
    for (int p = 0; p < 4; ++p) {
      int col = tx * 8 + 2 * p;
      float a = fmaxf(acc[i][2 * p] + bias[col], 0.f);
      float b = fmaxf(acc[i][2 * p + 1] + bias[col + 1], 0.f);
      orow[tx * 4 + p] = h2u(pk2(a, b));
    }
  }
}

// ---------------------------------------------------------------------------
// K3: decoder input projections
// ---------------------------------------------------------------------------
__global__ __launch_bounds__(256) void k_dec_gi(
    const float* __restrict__ Wih, const float* __restrict__ bih,
    const float* __restrict__ emb, float* __restrict__ gi) {
  __shared__ float e[4][32];
  const int c = blockIdx.x, tid = threadIdx.x;
  if (tid < 128) e[tid >> 5][tid & 31] = emb[tid];
  __syncthreads();
#pragma unroll
  for (int i = 0; i < 3; ++i) {
    int r = tid + i * 256;
    const float* w = Wih + ((size_t)c * 768 + r) * 32;
    float b = bih[(size_t)c * 768 + r];
    float a0 = b, a1 = b, a2 = b, a3 = b;
#pragma unroll
    for (int k = 0; k < 32; ++k) {
      float wv = w[k];
      a0 = fmaf(wv, e[0][k], a0);
      a1 = fmaf(wv, e[1][k], a1);
      a2 = fmaf(wv, e[2][k], a2);
      a3 = fmaf(wv, e[3][k], a3);
    }
    gi[((size_t)c * 4 + 0) * 768 + r] = a0;
    gi[((size_t)c * 4 + 1) * 768 + r] = a1;
    gi[((size_t)c * 4 + 2) * 768 + r] = a2;
    gi[((size_t)c * 4 + 3) * 768 + r] = a3;
  }
}

// ---------------------------------------------------------------------------
// K3b: pack dec_Whh (f32) -> f16x2 stream layout wpk[(c*32+ic)*768+tid] uint4.
// Chunk ic: kc=ic>>4, kk=(ic>>1)&7, half=ic&1; thread (w,q,m,mw) owns
// row 64w+16q+8kc+(kk^mw), cols [16m+8*half .. +7].
// ---------------------------------------------------------------------------
__global__ __launch_bounds__(768) void k_pack_dec(
    const float* __restrict__ Whh, uint4* __restrict__ wpk) {
  const int c = blockIdx.x >> 5, ic = blockIdx.x & 31;
  const int tid = threadIdx.x;
  const int w = tid >> 6, l = tid & 63, q = l >> 4, m = l & 15, mw = m & 7;
  const int kc = ic >> 4, kk = (ic >> 1) & 7, half = ic & 1;
  const int row = 64 * w + 16 * q + 8 * kc + (kk ^ mw);
  const float* src = Whh + ((size_t)c * 768 + row) * 256 + 16 * m + 8 * half;
  float4 a = *(const float4*)(src);
  float4 b = *(const float4*)(src + 4);
  wpk[((size_t)c * 32 + ic) * 768 + tid] = pack8u(a, b);
}

// ---------------------------------------------------------------------------
// K4: encoder GRU. 160 blocks x 512 threads. Weights: 13 uint4 chunks in
// registers (ci_0..7, sg_0..3, ch_0) + 11 chunks LDS-resident (ch_1..7 at
// slots 0..6, sg_4..7 at slots 7..10), loaded once in the prologue.
// ---------------------------------------------------------------------------
#define LD_CI(k)                                                              \
  uint4 ci_##k;                                                               \
  { int vc = 32 * w + 8 * q + ((k) ^ mw);                                     \
    const float4* pi = (const float4*)(Wih + (size_t)vc * 128 + 8 * m);       \
    ci_##k = pack8u(pi[0], pi[1]); }                                          \
  __builtin_amdgcn_sched_barrier(0);

#define LD_CH_REG(k)                                                          \
  uint4 ch_##k;                                                               \
  { int vc = 32 * w + 8 * q + ((k) ^ mw);                                     \
    const float4* ph = (const float4*)(Whh + (size_t)vc * 128 + 8 * m);       \
    ch_##k = pack8u(ph[0], ph[1]); }                                          \
  __builtin_amdgcn_sched_barrier(0);

#define LD_CH_LDS(k)                                                          \
  { int vc = 32 * w + 8 * q + ((k) ^ mw);                                     \
    const float4* ph = (const float4*)(Whh + (size_t)vc * 128 + 8 * m);       \
    wle[((k) - 1) * 512 + tid] = pack8u(ph[0], ph[1]); }                      \
  __builtin_amdgcn_sched_barrier(0);

#define LD_SG_REG(k)                                                          \
  uint4 sg_##k;                                                               \
  { int vc = 32 * w + 8 * q + ((k) ^ mw);                                     \
    int s = (w < 4) ? vc : (vc - 128);                                        \
    const float* sb2 = (w < 4) ? (Wih + (size_t)(256 + s) * 128)              \
                               : (Whh + (size_t)(256 + s) * 128);             \
    const float4* ps = (const float4*)(sb2 + 8 * m);                          \
    sg_##k = pack8u(ps[0], ps[1]); }                                          \
  __builtin_amdgcn_sched_barrier(0);

#define LD_SG_LDS(k)                                                          \
  { int vc = 32 * w + 8 * q + ((k) ^ mw);                                     \
    int s = (w < 4) ? vc : (vc - 128);                                        \
    const float* sb2 = (w < 4) ? (Wih + (size_t)(256 + s) * 128)              \
                               : (Whh + (size_t)(256 + s) * 128);             \
    const float4* ps = (const float4*)(sb2 + 8 * m);                          \
    wle[(7 + (k) - 4) * 512 + tid] = pack8u(ps[0], ps[1]); }                  \
  __builtin_amdgcn_sched_barrier(0);

__global__ __launch_bounds__(512) void k_enc_gru(
    const unsigned* __restrict__ encf2,
    const float* __restrict__ WihF, const float* __restrict__ WhhF,
    const float* __restrict__ bihF, const float* __restrict__ bhhF,
    const float* __restrict__ WihB, const float* __restrict__ WhhB,
    const float* __restrict__ bihB, const float* __restrict__ bhhB,
    float* __restrict__ dec_h0) {
  const int blk = blockIdx.x;
  const int c = blk >> 1, dir = blk & 1;
  const int tid = threadIdx.x;
  const int w = tid >> 6, l = tid & 63, q = l >> 4, m = l & 15, mw = m & 7;

  const float* Wih = (dir ? WihB : WihF) + (size_t)c * 384 * 128;
  const float* Whh = (dir ? WhhB : WhhF) + (size_t)c * 384 * 128;
  const float* bih = (dir ? bihB : bihF) + (size_t)c * 384;
  const float* bhh = (dir ? bhhB : bhhF) + (size_t)c * 384;

  __shared__ __align__(16) unsigned x2s[2][64];
  __shared__ __align__(16) unsigned h2s[64];
  __shared__ float aBuf[512];
  __shared__ uint4 wle[11 * 512];  // 90112 B, weights resident all 513 steps

  LD_CI(0) LD_CI(1) LD_CI(2) LD_CI(3) LD_CI(4) LD_CI(5) LD_CI(6) LD_CI(7)
  LD_CH_REG(0)
  LD_CH_LDS(1) LD_CH_LDS(2) LD_CH_LDS(3) LD_CH_LDS(4)
  LD_CH_LDS(5) LD_CH_LDS(6) LD_CH_LDS(7)
  LD_SG_REG(0) LD_SG_REG(1) LD_SG_REG(2) LD_SG_REG(3)
  LD_SG_LDS(4) LD_SG_LDS(5) LD_SG_LDS(6) LD_SG_LDS(7)

  float bown;
  int ownIdx;
  if (m < 8) {
    int vo = 32 * w + 8 * q + m;
    bown = bih[vo] + bhh[vo];
    ownIdx = vo;
  } else {
    int so = (w < 4) ? (32 * w + 8 * q + mw) : (32 * (w - 4) + 8 * q + mw);
    bown = (w < 4) ? bih[256 + so] : bhh[256 + so];
    ownIdx = (w < 4) ? (256 + so) : (384 + so);
  }

  if (tid < 64) h2s[tid] = 0u;
  if (tid >= 448) {
    int lane = tid - 448;
    x2s[0][lane] = (dir == 0) ? encf2[((size_t)c * 512 + 0) * 64 + lane] : 0x3C003C00u;
  }
  float hreg = 0.f;
  __syncthreads();

  const uint4* wl = wle + tid;

  for (int t = 0; t <= 512; ++t) {
    unsigned xpre = 0;
    if (tid >= 448 && t < 512) {
      int tn = t + 1, lane = tid - 448;
      int row = (dir == 0) ? ((tn < 512) ? tn : -1) : (512 - tn);
      xpre = (row < 0) ? 0x3C003C00u : encf2[((size_t)c * 512 + row) * 64 + lane];
    }
    uint4 xv = ((const uint4*)&x2s[t & 1][0])[m];
    uint4 hv = ((const uint4*)&h2s[0])[m];
    h2v x0 = u2h(xv.x), x1 = u2h(xv.y), x2 = u2h(xv.z), x3 = u2h(xv.w);
    h2v g0 = u2h(hv.x), g1 = u2h(hv.y), g2 = u2h(hv.z), g3 = u2h(hv.w);
    // pA: combined r/z rows (Wih.x + Whh.h)
    float p0 = dotu4(ci_0, x0, x1, x2, x3, dotu4(ch_0, g0, g1, g2, g3, 0.f));
    uint4 cv = wl[0 * 512];
    float p1 = dotu4(ci_1, x0, x1, x2, x3, dotu4(cv, g0, g1, g2, g3, 0.f));
    p0 = dppadd<0xB1>(p0, p1);
    cv = wl[1 * 512];
    float p2 = dotu4(ci_2, x0, x1, x2, x3, dotu4(cv, g0, g1, g2, g3, 0.f));
    cv = wl[2 * 512];
    float p3 = dotu4(ci_3, x0, x1, x2, x3, dotu4(cv, g0, g1, g2, g3, 0.f));
    p2 = dppadd<0xB1>(p2, p3);
    p0 = dppadd<0x4E>(p0, p2);
    cv = wl[3 * 512];
    float p4 = dotu4(ci_4, x0, x1, x2, x3, dotu4(cv, g0, g1, g2, g3, 0.f));
    cv = wl[4 * 512];
    float p5 = dotu4(ci_5, x0, x1, x2, x3, dotu4(cv, g0, g1, g2, g3, 0.f));
    p4 = dppadd<0xB1>(p4, p5);
    cv = wl[5 * 512];
    float p6 = dotu4(ci_6, x0, x1, x2, x3, dotu4(cv, g0, g1, g2, g3, 0.f));
    cv = wl[6 * 512];
    float p7 = dotu4(ci_7, x0, x1, x2, x3, dotu4(cv, g0, g1, g2, g3, 0.f));
    p6 = dppadd<0xB1>(p6, p7);
    p4 = dppadd<0x4E>(p4, p6);
    p0 = swz4add(p0, p4);
    float pA = dppadd<0x128>(p0, p0);
    // pB: single-gate rows (i_n for w<4, h_n for w>=4)
    h2v s0 = (w < 4) ? x0 : g0, s1 = (w < 4) ? x1 : g1;
    h2v s2 = (w < 4) ? x2 : g2, s3 = (w < 4) ? x3 : g3;
    float q0 = dotu4(sg_0, s0, s1, s2, s3, 0.f);
    float q1 = dotu4(sg_1, s0, s1, s2, s3, 0.f);
    q0 = dppadd<0xB1>(q0, q1);
    float q2 = dotu4(sg_2, s0, s1, s2, s3, 0.f);
    float q3 = dotu4(sg_3, s0, s1, s2, s3, 0.f);
    q2 = dppadd<0xB1>(q2, q3);
    q0 = dppadd<0x4E>(q0, q2);
    cv = wl[7 * 512];
    float q4 = dotu4(cv, s0, s1, s2, s3, 0.f);
    cv = wl[8 * 512];
    float q5 = dotu4(cv, s0, s1, s2, s3, 0.f);
    q4 = dppadd<0xB1>(q4, q5);
    cv = wl[9 * 512];
    float q6 = dotu4(cv, s0, s1, s2, s3, 0.f);
    cv = wl[10 * 512];
    float q7 = dotu4(cv, s0, s1, s2, s3, 0.f);
    q6 = dppadd<0xB1>(q6, q7);
    q4 = dppadd<0x4E>(q4, q6);
    q0 = swz4add(q0, q4);
    float pB = dppadd<0x128>(q0, q0);

    aBuf[ownIdx] = ((m < 8) ? pA : pB) + bown;
    __syncthreads();
    if (tid < 128) {
      float r = sigf(aBuf[tid]);
      float z = sigf(aBuf[128 + tid]);
      float nn = tanhfast(aBuf[256 + tid] + r * aBuf[384 + tid]);
      float hn = (1.f - z) * nn + z * hreg;
      hreg = hn;
      float other = __shfl_xor(hn, 1, 64);
      if ((tid & 1) == 0) h2s[tid >> 1] = h2u(pk2(hn, other));
    } else if (tid >= 448 && t < 512) {
      x2s[(t + 1) & 1][tid - 448] = xpre;
    }
    __syncthreads();
  }
  if (tid < 128) dec_h0[(size_t)c * 256 + dir * 128 + tid] = hreg;
}

// ---------------------------------------------------------------------------
// K5: decoder GRU + fused out-projection + log_softmax. 80 blocks x 768.
// Chunks 0..11 regs, 12..23 LDS-resident (147KB), 24..31 streamed via 4 slots
// with phase-interleave: {24,25},{26,27} at step start; {28,29} after pc0;
// {30,31} after LDS-pc1; reloads wrap so every load has >=600cy lead.
// gi rows prefetched from global per step (gisf removed from LDS).
// ---------------------------------------------------------------------------
#define CONSX(sa, sb, dst)                                                    \
  dst = dotu4(sb, g4, g5, g6, g7, dotu4(sa, g0, g1, g2, g3, 0.f));

#define BAR_LGKM()                                                            \
  asm volatile("s_waitcnt lgkmcnt(0)" ::: "memory");                          \
  __builtin_amdgcn_s_barrier();                                               \
  asm volatile("" ::: "memory");

__global__ __launch_bounds__(768) void k_dec_gru(
    const uint4* __restrict__ wpk, const float* __restrict__ bhh,
    const float* __restrict__ gi, const float* __restrict__ h0,
    const int* __restrict__ labels,
    const float* __restrict__ outW, const float* __restrict__ outB,
    float* __restrict__ out) {
  const int c = blockIdx.x, tid = threadIdx.x;
  const int w = tid >> 6, l = tid & 63, m = l & 15;

  __shared__ __align__(16) unsigned h2s[128];
  __shared__ float aBuf[768];
  __shared__ float owsh[1024];
  __shared__ int labs[513];
  __shared__ float red[4][4];
  __shared__ uint4 wlds[12 * 768];  // 147456 B, chunks 12..23 resident

  const uint4* wp = wpk + (size_t)c * 32 * 768 + tid;
  const uint4* wps = wp + 24 * 768;

  // stage chunks 12..23 into LDS (once)
  for (int j = 0; j < 12; ++j) wlds[j * 768 + tid] = wp[(12 + j) * 768];
  __builtin_amdgcn_sched_barrier(0);
  // register chunks 0..11
  uint4 ua0 = wp[0 * 768], ua1 = wp[1 * 768], ua2 = wp[2 * 768], ua3 = wp[3 * 768];
  uint4 ua4 = wp[4 * 768], ua5 = wp[5 * 768], ua6 = wp[6 * 768], ua7 = wp[7 * 768];
  uint4 ua8 = wp[8 * 768], ua9 = wp[9 * 768], ua10 = wp[10 * 768], ua11 = wp[11 * 768];
  __builtin_amdgcn_sched_barrier(0);
  // stream slots preload chunks 24..27
  uint4 sl0 = wps[0 * 768], sl1 = wps[1 * 768];
  uint4 sl2 = wps[2 * 768], sl3 = wps[3 * 768];

  float bown = bhh[(size_t)c * 768 + 64 * w + l];
  const float* gib = gi + (size_t)c * 4 * 768;
  for (int i = tid; i < 1024; i += 768) owsh[i] = outW[i];
  if (tid < 512) labs[tid + 1] = labels[(size_t)c * 512 + tid];
  if (tid == 512) labs[0] = 2;  // SOS
  float b0 = outB[0], b1 = outB[1], b2 = outB[2], b3 = outB[3];
  float hreg = 0.f;
  if (tid < 256) {
    hreg = h0[(size_t)c * 256 + tid];
    float other = __shfl_xor(hreg, 1, 64);
    if ((tid & 1) == 0) h2s[tid >> 1] = h2u(pk2(hreg, other));
  }
  __syncthreads();

  const uint4* wl = wlds + tid;

  for (int t = 0; t <= 512; ++t) {
    uint4 ha = ((const uint4*)h2s)[2 * m];
    uint4 hb = ((const uint4*)h2s)[2 * m + 1];
    h2v g0 = u2h(ha.x), g1 = u2h(ha.y), g2 = u2h(ha.z), g3 = u2h(ha.w);
    h2v g4 = u2h(hb.x), g5 = u2h(hb.y), g6 = u2h(hb.z), g7 = u2h(hb.w);
    // s1: stream k=4 (24,25), k=5 (26,27); reload 28..31
    float p4s, p5s, p6s, p7s;
    CONSX(sl0, sl1, p4s); sl0 = wps[4 * 768]; sl1 = wps[5 * 768];
    CONSX(sl2, sl3, p5s); sl2 = wps[6 * 768]; sl3 = wps[7 * 768];
    float q4 = dppadd<0xB1>(p4s, p5s);
    __builtin_amdgcn_sched_barrier(0);
    // gi prefetch for the gate phase
    int sel = labs[t];
    float gv0 = 0.f, gv1 = 0.f, gv2 = 0.f;
    if (tid < 256) {
      const float* gp = gib + sel * 768;
      gv0 = gp[tid]; gv1 = gp[tid + 256]; gv2 = gp[tid + 512];
    }
    // s2: pc0 = regs (k=0..5) + LDS chunks 12..15 (k=6,7)
    float p0, p1, p2, p3;
    CONSX(ua0, ua1, p0); CONSX(ua2, ua3, p1); p0 = dppadd<0xB1>(p0, p1);
    CONSX(ua4, ua5, p2); CONSX(ua6, ua7, p3); p2 = dppadd<0xB1>(p2, p3);
    p0 = dppadd<0x4E>(p0, p2);
    CONSX(ua8, ua9, p2); CONSX(ua10, ua11, p3); p2 = dppadd<0xB1>(p2, p3);
    uint4 cw0 = wl[0 * 768], cw1 = wl[1 * 768], cw2 = wl[2 * 768], cw3 = wl[3 * 768];
    float p6b, p7b;
    CONSX(cw0, cw1, p6b); CONSX(cw2, cw3, p7b); p6b = dppadd<0xB1>(p6b, p7b);
    p2 = dppadd<0x4E>(p2, p6b);
    p0 = swz4add(p0, p2);
    float pc0 = dppadd<0x128>(p0, p0);
    // s3: stream k=6 (28,29); reload 24',25' (next step)
    CONSX(sl0, sl1, p6s); sl0 = wps[0 * 768]; sl1 = wps[1 * 768];
    __builtin_amdgcn_sched_barrier(0);
    // s4: pc1 LDS part k=0..3 (chunks 16..23)
    cw0 = wl[4 * 768]; cw1 = wl[5 * 768]; cw2 = wl[6 * 768]; cw3 = wl[7 * 768];
    CONSX(cw0, cw1, p0); CONSX(cw2, cw3, p1); p0 = dppadd<0xB1>(p0, p1);
    cw0 = wl[8 * 768]; cw1 = wl[9 * 768]; cw2 = wl[10 * 768]; cw3 = wl[11 * 768];
    CONSX(cw0, cw1, p2); CONSX(cw2, cw3, p3); p2 = dppadd<0xB1>(p2, p3);
    p0 = dppadd<0x4E>(p0, p2);
    // s5: stream k=7 (30,31); reload 26',27'
    CONSX(sl2, sl3, p7s); sl2 = wps[2 * 768]; sl3 = wps[3 * 768];
    float q6 = dppadd<0xB1>(p6s, p7s);
    q4 = dppadd<0x4E>(q4, q6);
    p0 = swz4add(p0, q4);
    float pc1 = dppadd<0x128>(p0, p0);

    aBuf[64 * w + l] = ((m < 8) ? pc0 : pc1) + bown;
    BAR_LGKM();
    if (tid < 256) {
      float r = sigf(gv0 + aBuf[tid]);
      float z = sigf(gv1 + aBuf[256 + tid]);
      float nn = tanhfast(gv2 + r * aBuf[512 + tid]);
      float hn = (1.f - z) * nn + z * hreg;
      hreg = hn;
      float other = __shfl_xor(hn, 1, 64);
      if ((tid & 1) == 0) h2s[tid >> 1] = h2u(pk2(hn, other));
      float p0o = owsh[tid] * hn, p1o = owsh[256 + tid] * hn;
      float p2o = owsh[512 + tid] * hn, p3o = owsh[768 + tid] * hn;
#pragma unroll
      for (int off = 32; off > 0; off >>= 1) {
        p0o += __shfl_xor(p0o, off, 64);
        p1o += __shfl_xor(p1o, off, 64);
        p2o += __shfl_xor(p2o, off, 64);
        p3o += __shfl_xor(p3o, off, 64);
      }
      if ((tid & 63) == 0) {
        int ww = tid >> 6;
        red[ww][0] = p0o; red[ww][1] = p1o; red[ww][2] = p2o; red[ww][3] = p3o;
      }
    }
    BAR_LGKM();
    if (tid == 0) {
      float l0 = red[0][0] + red[1][0] + red[2][0] + red[3][0] + b0;
      float l1 = red[0][1] + red[1][1] + red[2][1] + red[3][1] + b1;
      float l2 = red[0][2] + red[1][2] + red[2][2] + red[3][2] + b2;
      float l3 = red[0][3] + red[1][3] + red[2][3] + red[3][3] + b3;
      float mm = fmaxf(fmaxf(l0, l1), fmaxf(l2, l3));
      float s = __expf(l0 - mm) + __expf(l1 - mm) + __expf(l2 - mm) + __expf(l3 - mm);
      float lse = mm + __logf(s);
      float* o = out + ((size_t)c * 513 + t) * 4;
      o[0] = l0 - lse; o[1] = l1 - lse; o[2] = l2 - lse; o[3] = l3 - lse;
    }
  }
}

// ---------------------------------------------------------------------------
// K6: labels (as float) and weights passthrough
// ---------------------------------------------------------------------------
__global__ void k_passthrough(const int* __restrict__ labels,
                              const float* __restrict__ weights,
                              float* __restrict__ out) {
  int i = blockIdx.x * blockDim.x + threadIdx.x;
  if (i < 40960) {
    out[164160 + i] = (float)labels[i];
    out[164160 + 40960 + i] = weights[i];
  }
}

// ---------------------------------------------------------------------------
extern "C" void kernel_launch(void* const* d_in, const int* in_sizes, int n_in,
                              void* d_out, int out_size, void* d_ws, size_t ws_size,
                              hipStream_t stream) {
  (void)in_sizes; (void)n_in; (void)out_size; (void)ws_size;
  const float* feat = (const float*)d_in[0];
  const float* score = (const float*)d_in[1];
  const float* box = (const float*)d_in[2];
  const float* orig = (const float*)d_in[3];
  const int* labels = (const int*)d_in[4];
  const float* weights = (const float*)d_in[5];
  const float* appear_W = (const float*)d_in[8];
  const float* appear_b = (const float*)d_in[9];
  const float* featlin_W = (const float*)d_in[10];
  const float* featlin_b = (const float*)d_in[11];
  const float* eWihF = (const float*)d_in[12];
  const float* eWhhF = (const float*)d_in[13];
  const float* ebihF = (const float*)d_in[14];
  const float* ebhhF = (const float*)d_in[15];
  const float* eWihB = (const float*)d_in[16];
  const float* eWhhB = (const float*)d_in[17];
  const float* ebihB = (const float*)d_in[18];
  const float* ebhhB = (const float*)d_in[19];
  const float* dec_emb = (const float*)d_in[20];
  const float* dWih = (const float*)d_in[21];
  const float* dWhh = (const float*)d_in[22];
  const float* dbih = (const float*)d_in[23];
  const float* dbhh = (const float*)d_in[24];
  const float* outW = (const float*)d_in[25];
  const float* outB = (const float*)d_in[26];
  float* out = (float*)d_out;

  char* ws = (char*)d_ws;
  float* allf = (float*)ws;                                     // 40960*224 f32 (36.7MB)
  unsigned* encf2 = (unsigned*)(ws + (size_t)40960 * 224 * 4);  // 40960*64 u32
  float* dec_h0 = (float*)(ws + (size_t)40960 * 224 * 4 + (size_t)40960 * 64 * 4);
  float* dec_gi = dec_h0 + 80 * 256;                            // 80*4*768 f32
  // after k_gemm_featlin, allf is dead -> reuse it for the packed f16 weights
  uint4* wpack = (uint4*)allf;                                  // 80*32*768*16B = 31.5MB

  k_fill_misc<<<15360, 256, 0, stream>>>(score, box, orig, allf);
  k_gemm_appear<<<640, 256, 0, stream>>>(feat, appear_W, appear_b, allf);
  k_gemm_featlin<<<640, 256, 0, stream>>>(allf, featlin_W, featlin_b, encf2);
  k_pack_dec<<<80 * 32, 768, 0, stream>>>(dWhh, wpack);
  k_dec_gi<<<80, 256, 0, stream>>>(dWih, dbih, dec_emb, dec_gi);
  k_enc_gru<<<160, 512, 0, stream>>>(encf2, eWihF, eWhhF, ebihF, ebhhF,
                                     eWihB, eWhhB, ebihB, ebhhB, dec_h0);
  k_dec_gru<<<80, 768, 0, stream>>>(wpack, dbhh, dec_gi, dec_h0, labels, outW, outB, out);
  k_passthrough<<<160, 256, 0, stream>>>(labels, weights, out);
}

// Round 11
// 1595.490 us; speedup vs baseline: 1.1399x; 1.0633x over previous
//
#include <hip/hip_runtime.h>

// ---------------------------------------------------------------------------
// Encoder_Decoder v11 = v10 with two correctness fixes:
//  (a) dec_h0 writer guard dropped the erroneous tid<256 clause (units 64..127
//      were never written -> decoder started from poisoned h0).
//  (b) h2s double-buffered in both GRU loops: v10's single end-of-step barrier
//      left the top-of-step h2s READ and end-of-step h2s WRITE of the same
//      buffer unordered across waves (race). Ping-pong read[t&1]/write[(t+1)&1]
//      is safe with one barrier.
// Structure unchanged: fused-gate groups (all 3 gates land on one lane after
// the XOR-slot DPP reduce), 1 lgkm-only barrier/step, deferred out-projection
// (k_out over 41040 independent rows), three-pipe weight delivery.
// ---------------------------------------------------------------------------

typedef __fp16 h2v __attribute__((ext_vector_type(2)));

__device__ __forceinline__ h2v pk2(float a, float b) {
  return __builtin_amdgcn_cvt_pkrtz(a, b);
}
__device__ __forceinline__ unsigned h2u(h2v h) { return __builtin_bit_cast(unsigned, h); }
__device__ __forceinline__ h2v u2h(unsigned u) { return __builtin_bit_cast(h2v, u); }
__device__ __forceinline__ float fdot2f(h2v a, h2v b, float c) {
  return __builtin_amdgcn_fdot2(a, b, c, false);
}
__device__ __forceinline__ float sigf(float x) { return 1.f / (1.f + __expf(-x)); }
__device__ __forceinline__ float tanhfast(float x) { return 2.f / (1.f + __expf(-2.f * x)) - 1.f; }

__device__ __forceinline__ uint4 pack8u(float4 a, float4 b) {
  uint4 o;
  o.x = h2u(pk2(a.x, a.y)); o.y = h2u(pk2(a.z, a.w));
  o.z = h2u(pk2(b.x, b.y)); o.w = h2u(pk2(b.z, b.w));
  return o;
}

__device__ __forceinline__ float dotu4(uint4 cv, h2v a0, h2v a1, h2v a2, h2v a3,
                                       float acc) {
  acc = fdot2f(u2h(cv.x), a0, acc);
  acc = fdot2f(u2h(cv.y), a1, acc);
  acc = fdot2f(u2h(cv.z), a2, acc);
  acc = fdot2f(u2h(cv.w), a3, acc);
  return acc;
}

template <int CTRL>
__device__ __forceinline__ float dppadd(float acc, float v) {
  int r = __builtin_amdgcn_update_dpp(0, __float_as_int(v), CTRL, 0xF, 0xF, true);
  return acc + __int_as_float(r);
}
__device__ __forceinline__ float swz4add(float acc, float v) {
  return acc + __int_as_float(__builtin_amdgcn_ds_swizzle(__float_as_int(v), 0x101F));
}

// 8 partials, slot k on lane holds row-id k^(m&7); returns row-id (m&7) sum.
__device__ __forceinline__ float reduce8s(float p0, float p1, float p2, float p3,
                                          float p4, float p5, float p6, float p7) {
  p0 = dppadd<0xB1>(p0, p1);
  p2 = dppadd<0xB1>(p2, p3);
  p4 = dppadd<0xB1>(p4, p5);
  p6 = dppadd<0xB1>(p6, p7);
  p0 = dppadd<0x4E>(p0, p2);
  p4 = dppadd<0x4E>(p4, p6);
  p0 = swz4add(p0, p4);
  p0 = dppadd<0x128>(p0, p0);
  return p0;
}

#define BAR_LGKM()                                     \
  asm volatile("s_waitcnt lgkmcnt(0)" ::: "memory");   \
  __builtin_amdgcn_s_barrier();                        \
  asm volatile("" ::: "memory");

// ---------------------------------------------------------------------------
// K0: fill allf[:,128:224]
// ---------------------------------------------------------------------------
__global__ void k_fill_misc(const float* __restrict__ score, const float* __restrict__ box,
                            const float* __restrict__ orig, float* __restrict__ allf) {
  int i = blockIdx.x * blockDim.x + threadIdx.x;
  if (i >= 40960 * 96) return;
  int row = i / 96, k = i - row * 96;
  float v;
  if (k == 0) v = score[row];
  else if (k < 5) v = box[row * 4 + (k - 1)];
  else v = orig[(size_t)row * 91 + (k - 5)];
  allf[(size_t)row * 224 + 128 + k] = v;
}

// ---------------------------------------------------------------------------
// K1: allf[:,0:128] = relu(feat @ appear_W^T + appear_b)
// ---------------------------------------------------------------------------
__global__ __launch_bounds__(256) void k_gemm_appear(
    const float* __restrict__ A, const float* __restrict__ W,
    const float* __restrict__ bias, float* __restrict__ allf) {
  __shared__ float As[32][68];
  __shared__ float Ws[32][132];
  const int tid = threadIdx.x;
  const int tx = tid & 15, ty = tid >> 4;
  const int r0 = blockIdx.x * 64;
  const int lr = tid >> 3;
  const int lk = (tid & 7) * 4;
  float acc[4][8];
#pragma unroll
  for (int i = 0; i < 4; ++i)
#pragma unroll
    for (int j = 0; j < 8; ++j) acc[i][j] = 0.f;

  for (int k0 = 0; k0 < 1024; k0 += 32) {
#pragma unroll
    for (int i = 0; i < 2; ++i) {
      int rr = lr + i * 32;
      float4 v = *(const float4*)(A + (size_t)(r0 + rr) * 1024 + k0 + lk);
      As[lk + 0][rr] = v.x; As[lk + 1][rr] = v.y; As[lk + 2][rr] = v.z; As[lk + 3][rr] = v.w;
    }
#pragma unroll
    for (int i = 0; i < 4; ++i) {
      int wr = lr + i * 32;
      float4 v = *(const float4*)(W + (size_t)wr * 1024 + k0 + lk);
      Ws[lk + 0][wr] = v.x; Ws[lk + 1][wr] = v.y; Ws[lk + 2][wr] = v.z; Ws[lk + 3][wr] = v.w;
    }
    __syncthreads();
#pragma unroll
    for (int kk = 0; kk < 32; ++kk) {
      float4 a = *(const float4*)&As[kk][ty * 4];
      float4 w0 = *(const float4*)&Ws[kk][tx * 8];
      float4 w1 = *(const float4*)&Ws[kk][tx * 8 + 4];
      float av[4] = {a.x, a.y, a.z, a.w};
      float wv[8] = {w0.x, w0.y, w0.z, w0.w, w1.x, w1.y, w1.z, w1.w};
#pragma unroll
      for (int i = 0; i < 4; ++i)
#pragma unroll
        for (int j = 0; j < 8; ++j) acc[i][j] = fmaf(av[i], wv[j], acc[i][j]);
    }
    __syncthreads();
  }
#pragma unroll
  for (int i = 0; i < 4; ++i) {
    int row = r0 + ty * 4 + i;
#pragma unroll
    for (int j = 0; j < 8; ++j) {
      int col = tx * 8 + j;
      float v = acc[i][j] + bias[col];
      allf[(size_t)row * 224 + col] = fmaxf(v, 0.f);
    }
  }
}

// ---------------------------------------------------------------------------
// K2: enc_feat = relu(allf @ featlin_W^T + b), stored packed f16x2
// ---------------------------------------------------------------------------
__global__ __launch_bounds__(256) void k_gemm_featlin(
    const float* __restrict__ A, const float* __restrict__ W,
    const float* __restrict__ bias, unsigned* __restrict__ encf2) {
  __shared__ float As[32][68];
  __shared__ float Ws[32][132];
  const int tid = threadIdx.x;
  const int tx = tid & 15, ty = tid >> 4;
  const int r0 = blockIdx.x * 64;
  const int lr = tid >> 3;
  const int lk = (tid & 7) * 4;
  float acc[4][8];
#pragma unroll
  for (int i = 0; i < 4; ++i)
#pragma unroll
    for (int j = 0; j < 8; ++j) acc[i][j] = 0.f;

  for (int k0 = 0; k0 < 224; k0 += 32) {
#pragma unroll
    for (int i = 0; i < 2; ++i) {
      int rr = lr + i * 32;
      float4 v = *(const float4*)(A + (size_t)(r0 + rr) * 224 + k0 + lk);
      As[lk + 0][rr] = v.x; As[lk + 1][rr] = v.y; As[lk + 2][rr] = v.z; As[lk + 3][rr] = v.w;
    }
#pragma unroll
    for (int i = 0; i < 4; ++i) {
      int wr = lr + i * 32;
      float4 v = *(const float4*)(W + (size_t)wr * 224 + k0 + lk);
      Ws[lk + 0][wr] = v.x; Ws[lk + 1][wr] = v.y; Ws[lk + 2][wr] = v.z; Ws[lk + 3][wr] = v.w;
    }
    __syncthreads();
#pragma unroll
    for (int kk = 0; kk < 32; ++kk) {
      float4 a = *(const float4*)&As[kk][ty * 4];
      float4 w0 = *(const float4*)&Ws[kk][tx * 8];
      float4 w1 = *(const float4*)&Ws[kk][tx * 8 + 4];
      float av[4] = {a.x, a.y, a.z, a.w};
      float wv[8] = {w0.x, w0.y, w0.z, w0.w, w1.x, w1.y, w1.z, w1.w};
#pragma unroll
      for (int i = 0; i < 4; ++i)
#pragma unroll
        for (int j = 0; j < 8; ++j) acc[i][j] = fmaf(av[i], wv[j], acc[i][j]);
    }
    __syncthreads();
  }
#pragma unroll
  for (int i = 0; i < 4; ++i) {
    int row = r0 + ty * 4 + i;
    unsigned* orow = encf2 + (size_t)row * 64;
#pragma unroll
    for (int p = 0; p < 4; ++p) {
      int col = tx * 8 + 2 * p;
      float a = fmaxf(acc[i][2 * p] + bias[col], 0.f);
      float b = fmaxf(acc[i][2 * p + 1] + bias[col + 1], 0.f);
      orow[tx * 4 + p] = h2u(pk2(a, b));
    }
  }
}

// ---------------------------------------------------------------------------
// K3: decoder input projections gi[c][v][r] (bih folded in)
// ---------------------------------------------------------------------------
__global__ __launch_bounds__(256) void k_dec_gi(
    const float* __restrict__ Wih, const float* __restrict__ bih,
    const float* __restrict__ emb, float* __restrict__ gi) {
  __shared__ float e[4][32];
  const int c = blockIdx.x, tid = threadIdx.x;
  if (tid < 128) e[tid >> 5][tid & 31] = emb[tid];
  __syncthreads();
#pragma unroll
  for (int i = 0; i < 3; ++i) {
    int r = tid + i * 256;
    const float* w = Wih + ((size_t)c * 768 + r) * 32;
    float b = bih[(size_t)c * 768 + r];
    float a0 = b, a1 = b, a2 = b, a3 = b;
#pragma unroll
    for (int k = 0; k < 32; ++k) {
      float wv = w[k];
      a0 = fmaf(wv, e[0][k], a0);
      a1 = fmaf(wv, e[1][k], a1);
      a2 = fmaf(wv, e[2][k], a2);
      a3 = fmaf(wv, e[3][k], a3);
    }
    gi[((size_t)c * 4 + 0) * 768 + r] = a0;
    gi[((size_t)c * 4 + 1) * 768 + r] = a1;
    gi[((size_t)c * 4 + 2) * 768 + r] = a2;
    gi[((size_t)c * 4 + 3) * 768 + r] = a3;
  }
}

// ---------------------------------------------------------------------------
// K3b: pack dec_Whh -> f16 chunks. ic = gt*16 + k*2 + hf. Thread (G,m,mw):
// row = gt*256 + 8G + (k^mw), cols 16m+8hf..+7.
// ---------------------------------------------------------------------------
__global__ __launch_bounds__(512) void k_pack_dec(
    const float* __restrict__ Whh, uint4* __restrict__ wpk) {
  const int c = blockIdx.x / 48, ic = blockIdx.x % 48;
  const int tid = threadIdx.x;
  const int G = tid >> 4, m = tid & 15, mw = m & 7;
  const int gt = ic >> 4, k = (ic & 15) >> 1, hf = ic & 1;
  const int row = gt * 256 + 8 * G + (k ^ mw);
  const float* src = Whh + ((size_t)c * 768 + row) * 256 + 16 * m + 8 * hf;
  wpk[((size_t)c * 48 + ic) * 512 + tid] =
      pack8u(*(const float4*)src, *(const float4*)(src + 4));
}

// ---------------------------------------------------------------------------
// K4: encoder GRU, fused gates, 1 barrier/step. 160 blocks x 512 threads.
// Group (16 lanes) owns 4 units; 8 XOR slots = 4 units x 2 sources (Wih/Whh).
// Chunks: gate r (k0..7) + z (k0..3) in regs; z (k4..7) + n (k0..7) in LDS.
// h2s double-buffered (race fix).
// ---------------------------------------------------------------------------
#define ELOAD(gt, k, DST)                                                          \
  {                                                                                \
    int rid_ = (k) ^ mw;                                                           \
    const float* Mx_ = ((k) & 1) ? baseB : baseA;                                  \
    const float4* ps_ =                                                            \
        (const float4*)(Mx_ + ((size_t)((gt) * 128 + 4 * G + (rid_ >> 1))) * 128 + \
                        8 * m);                                                    \
    DST = pack8u(ps_[0], ps_[1]);                                                  \
  }                                                                                \
  __builtin_amdgcn_sched_barrier(0);

__global__ __launch_bounds__(512) void k_enc_gru(
    const unsigned* __restrict__ encf2,
    const float* __restrict__ WihF, const float* __restrict__ WhhF,
    const float* __restrict__ bihF, const float* __restrict__ bhhF,
    const float* __restrict__ WihB, const float* __restrict__ WhhB,
    const float* __restrict__ bihB, const float* __restrict__ bhhB,
    float* __restrict__ dec_h0) {
  const int blk = blockIdx.x;
  const int c = blk >> 1, dir = blk & 1;
  const int tid = threadIdx.x;
  const int G = tid >> 4, m = tid & 15, mw = m & 7;

  const float* Wih = (dir ? WihB : WihF) + (size_t)c * 384 * 128;
  const float* Whh = (dir ? WhhB : WhhF) + (size_t)c * 384 * 128;
  const float* bih = (dir ? bihB : bihF) + (size_t)c * 384;
  const float* bhh = (dir ? bhhB : bhhF) + (size_t)c * 384;

  const float* baseA = (mw & 1) ? Whh : Wih;  // for even k
  const float* baseB = (mw & 1) ? Wih : Whh;  // for odd  k

  __shared__ __align__(16) unsigned x2s[2][64];
  __shared__ __align__(16) unsigned h2s[2][64];  // double-buffered (race fix)
  __shared__ __align__(16) uint4 wle[12 * 512];  // 98304 B

  // reg chunks: r k0..7, z k0..3
  uint4 er0, er1, er2, er3, er4, er5, er6, er7, ez0, ez1, ez2, ez3;
  ELOAD(0, 0, er0) ELOAD(0, 1, er1) ELOAD(0, 2, er2) ELOAD(0, 3, er3)
  ELOAD(0, 4, er4) ELOAD(0, 5, er5) ELOAD(0, 6, er6) ELOAD(0, 7, er7)
  ELOAD(1, 0, ez0) ELOAD(1, 1, ez1) ELOAD(1, 2, ez2) ELOAD(1, 3, ez3)
  // LDS chunks: z k4..7 -> 0..3; n k0..7 -> 4..11
  {
    uint4 t0;
    ELOAD(1, 4, t0) wle[0 * 512 + tid] = t0;
    ELOAD(1, 5, t0) wle[1 * 512 + tid] = t0;
    ELOAD(1, 6, t0) wle[2 * 512 + tid] = t0;
    ELOAD(1, 7, t0) wle[3 * 512 + tid] = t0;
    ELOAD(2, 0, t0) wle[4 * 512 + tid] = t0;
    ELOAD(2, 1, t0) wle[5 * 512 + tid] = t0;
    ELOAD(2, 2, t0) wle[6 * 512 + tid] = t0;
    ELOAD(2, 3, t0) wle[7 * 512 + tid] = t0;
    ELOAD(2, 4, t0) wle[8 * 512 + tid] = t0;
    ELOAD(2, 5, t0) wle[9 * 512 + tid] = t0;
    ELOAD(2, 6, t0) wle[10 * 512 + tid] = t0;
    ELOAD(2, 7, t0) wle[11 * 512 + tid] = t0;
  }

  const int u = 4 * G + (mw >> 1);
  const float brz_r = bih[u] + bhh[u];
  const float brz_z = bih[128 + u] + bhh[128 + u];
  const float b_in = bih[256 + u];
  const float b_hn = bhh[256 + u];

  if (tid < 64) h2s[0][tid] = 0u;
  if (tid >= 448) {
    int lane = tid - 448;
    x2s[0][lane] = (dir == 0) ? encf2[((size_t)c * 512 + 0) * 64 + lane] : 0x3C003C00u;
  }
  float hreg = 0.f;
  __syncthreads();

  const uint4* wl = wle + tid;

  for (int t = 0; t <= 512; ++t) {
    unsigned xpre = 0;
    if (tid >= 448 && t < 512) {
      int tn = t + 1, lane = tid - 448;
      int row = (dir == 0) ? ((tn < 512) ? tn : -1) : (512 - tn);
      xpre = (row < 0) ? 0x3C003C00u : encf2[((size_t)c * 512 + row) * 64 + lane];
    }
    uint4 xv = ((const uint4*)&x2s[t & 1][0])[m];
    uint4 hv = ((const uint4*)&h2s[t & 1][0])[m];
    h2v x0 = u2h(xv.x), x1 = u2h(xv.y), x2 = u2h(xv.z), x3 = u2h(xv.w);
    h2v hh0 = u2h(hv.x), hh1 = u2h(hv.y), hh2 = u2h(hv.z), hh3 = u2h(hv.w);
    bool oddl = (mw & 1);
    h2v a0 = oddl ? hh0 : x0, a1 = oddl ? hh1 : x1, a2 = oddl ? hh2 : x2, a3 = oddl ? hh3 : x3;
    h2v b0 = oddl ? x0 : hh0, b1 = oddl ? x1 : hh1, b2 = oddl ? x2 : hh2, b3 = oddl ? x3 : hh3;
#define EA(ch) dotu4(ch, a0, a1, a2, a3, 0.f)
#define EB(ch) dotu4(ch, b0, b1, b2, b3, 0.f)
    float vR = reduce8s(EA(er0), EB(er1), EA(er2), EB(er3),
                        EA(er4), EB(er5), EA(er6), EB(er7));
    float vZ = reduce8s(EA(ez0), EB(ez1), EA(ez2), EB(ez3),
                        EA(wl[0 * 512]), EB(wl[1 * 512]), EA(wl[2 * 512]), EB(wl[3 * 512]));
    float vN = reduce8s(EA(wl[4 * 512]), EB(wl[5 * 512]), EA(wl[6 * 512]), EB(wl[7 * 512]),
                        EA(wl[8 * 512]), EB(wl[9 * 512]), EA(wl[10 * 512]), EB(wl[11 * 512]));
#undef EA
#undef EB
    float oR = __shfl_xor(vR, 1, 64);
    float oZ = __shfl_xor(vZ, 1, 64);
    float oN = __shfl_xor(vN, 1, 64);
    float r = sigf(vR + oR + brz_r);
    float z = sigf(vZ + oZ + brz_z);
    float i_n = oddl ? oN : vN;
    float h_n = oddl ? vN : oN;
    float n = tanhfast(i_n + b_in + r * (h_n + b_hn));
    float hn = (1.f - z) * n + z * hreg;
    hreg = hn;
    float prt = __shfl_xor(hn, 2, 64);
    if (m < 8 && (mw & 3) == 0) h2s[(t + 1) & 1][2 * G + (mw >> 2)] = h2u(pk2(hn, prt));
    if (tid >= 448 && t < 512) x2s[(t + 1) & 1][tid - 448] = xpre;
    BAR_LGKM();
  }
  if ((m < 8) && ((mw & 1) == 0))  // FIX: all 512 threads participate (u 0..127)
    dec_h0[(size_t)c * 256 + dir * 128 + u] = hreg;
}

// ---------------------------------------------------------------------------
// K5: decoder GRU, fused gates, 1 barrier/step, deferred out-proj.
// 80 blocks x 512 threads. Group owns 8 units x 3 gates.
// Chunks ic0..11 regs, ic12..30 LDS, ic31..46 8-slot stream, ic47 direct.
// h2s double-buffered (race fix). Stores packed-f16 h to dhs2 each step.
// ---------------------------------------------------------------------------
#define CONSX(sa, sb) dotu4(sb, g4, g5, g6, g7, dotu4(sa, g0, g1, g2, g3, 0.f))

__global__ __launch_bounds__(512) void k_dec_gru(
    const uint4* __restrict__ wpk, const float* __restrict__ bhh,
    const float* __restrict__ gi, const float* __restrict__ h0,
    const int* __restrict__ labels, unsigned* __restrict__ dhs2) {
  const int c = blockIdx.x, tid = threadIdx.x;
  const int G = tid >> 4, m = tid & 15, mw = m & 7;

  __shared__ __align__(16) unsigned h2s[2][128];  // double-buffered (race fix)
  __shared__ int labs[513];
  __shared__ __align__(16) uint4 wlds[19 * 512];  // 155648 B

  const uint4* wp = wpk + (size_t)c * 48 * 512 + tid;
  const uint4* wpS = wp + 31 * 512;

  // LDS-resident chunks ic12..30
  for (int j = 0; j < 19; ++j) wlds[j * 512 + tid] = wp[(12 + j) * 512];
  __builtin_amdgcn_sched_barrier(0);
  // reg chunks ic0..11
  uint4 ua0 = wp[0 * 512], ua1 = wp[1 * 512], ua2 = wp[2 * 512], ua3 = wp[3 * 512];
  uint4 ua4 = wp[4 * 512], ua5 = wp[5 * 512], ua6 = wp[6 * 512], ua7 = wp[7 * 512];
  uint4 ua8 = wp[8 * 512], ua9 = wp[9 * 512], ua10 = wp[10 * 512], ua11 = wp[11 * 512];
  __builtin_amdgcn_sched_barrier(0);
  // stream slots: ic31..38
  uint4 sl0 = wpS[0 * 512], sl1 = wpS[1 * 512], sl2 = wpS[2 * 512], sl3 = wpS[3 * 512];
  uint4 sl4 = wpS[4 * 512], sl5 = wpS[5 * 512], sl6 = wpS[6 * 512], sl7 = wpS[7 * 512];

  const int u = 8 * G + mw;
  const float bb0 = bhh[(size_t)c * 768 + u];
  const float bb1 = bhh[(size_t)c * 768 + 256 + u];
  const float bb2 = bhh[(size_t)c * 768 + 512 + u];
  const float* gib = gi + (size_t)c * 4 * 768;
  unsigned* dout = dhs2 + (size_t)c * 513 * 128 + 4 * G + (mw >> 1);

  if (tid < 512) labs[tid + 1] = labels[(size_t)c * 512 + tid];
  if (tid == 0) labs[0] = 2;  // SOS
  float hreg = h0[(size_t)c * 256 + u];
  {
    float oth = __shfl_xor(hreg, 1, 64);
    if (m < 8 && (mw & 1) == 0) h2s[0][4 * G + (mw >> 1)] = h2u(pk2(hreg, oth));
  }
  __syncthreads();

  const uint4* wl = wlds + tid;

  for (int t = 0; t <= 512; ++t) {
    uint4 ha = ((const uint4*)&h2s[t & 1][0])[2 * m];
    uint4 hb = ((const uint4*)&h2s[t & 1][0])[2 * m + 1];
    h2v g0 = u2h(ha.x), g1 = u2h(ha.y), g2 = u2h(ha.z), g3 = u2h(ha.w);
    h2v g4 = u2h(hb.x), g5 = u2h(hb.y), g6 = u2h(hb.z), g7 = u2h(hb.w);
    int sel = labs[t];
    const float* gp = gib + sel * 768;
    float giR = gp[u], giZ = gp[256 + u], giN = gp[512 + u];
    uint4 dj = wp[47 * 512];  // direct chunk, ~full-step lead
    // --- r batch: ic0..15
    float p0 = CONSX(ua0, ua1), p1 = CONSX(ua2, ua3);
    float p2 = CONSX(ua4, ua5), p3 = CONSX(ua6, ua7);
    float p4 = CONSX(ua8, ua9), p5 = CONSX(ua10, ua11);
    float p6 = CONSX(wl[0 * 512], wl[1 * 512]);
    float p7 = CONSX(wl[2 * 512], wl[3 * 512]);
    float rsum = reduce8s(p0, p1, p2, p3, p4, p5, p6, p7);
    // --- z batch: ic16..31 (LDS 4..18 + sl0)
    p0 = CONSX(wl[4 * 512], wl[5 * 512]);
    p1 = CONSX(wl[6 * 512], wl[7 * 512]);
    p2 = CONSX(wl[8 * 512], wl[9 * 512]);
    p3 = CONSX(wl[10 * 512], wl[11 * 512]);
    p4 = CONSX(wl[12 * 512], wl[13 * 512]);
    p5 = CONSX(wl[14 * 512], wl[15 * 512]);
    p6 = CONSX(wl[16 * 512], wl[17 * 512]);
    p7 = CONSX(wl[18 * 512], sl0);
    sl0 = wpS[8 * 512];  // ic39
    float zsum = reduce8s(p0, p1, p2, p3, p4, p5, p6, p7);
    // --- n batch: ic32..47
    p0 = CONSX(sl1, sl2); sl1 = wpS[9 * 512]; sl2 = wpS[10 * 512];   // 40,41
    p1 = CONSX(sl3, sl4); sl3 = wpS[11 * 512]; sl4 = wpS[12 * 512];  // 42,43
    p2 = CONSX(sl5, sl6); sl5 = wpS[13 * 512]; sl6 = wpS[14 * 512];  // 44,45
    p3 = CONSX(sl7, sl0); sl7 = wpS[15 * 512]; sl0 = wpS[0 * 512];   // 46; next 31
    p4 = CONSX(sl1, sl2); sl1 = wpS[1 * 512]; sl2 = wpS[2 * 512];
    p5 = CONSX(sl3, sl4); sl3 = wpS[3 * 512]; sl4 = wpS[4 * 512];
    p6 = CONSX(sl5, sl6); sl5 = wpS[5 * 512]; sl6 = wpS[6 * 512];
    p7 = CONSX(sl7, dj);  sl7 = wpS[7 * 512];
    float nsum = reduce8s(p0, p1, p2, p3, p4, p5, p6, p7);
    // --- fused gates (all on this lane)
    float r = sigf(giR + rsum + bb0);
    float z = sigf(giZ + zsum + bb1);
    float n = tanhfast(giN + r * (nsum + bb2));
    float hn = (1.f - z) * n + z * hreg;
    hreg = hn;
    float oth = __shfl_xor(hn, 1, 64);
    if (m < 8 && (mw & 1) == 0) {
      unsigned pk = h2u(pk2(hn, oth));
      h2s[(t + 1) & 1][4 * G + (mw >> 1)] = pk;
      dout[(size_t)t * 128] = pk;
    }
    BAR_LGKM();
  }
}

// ---------------------------------------------------------------------------
// K5b: out-projection + log_softmax over 41040 rows (1 wave/row).
// ---------------------------------------------------------------------------
__global__ __launch_bounds__(256) void k_out(
    const unsigned* __restrict__ dhs2, const float* __restrict__ outW,
    const float* __restrict__ outB, float* __restrict__ out) {
  int row = blockIdx.x * 4 + (threadIdx.x >> 6);
  if (row >= 41040) return;
  int lane = threadIdx.x & 63;
  const unsigned* hp = dhs2 + (size_t)row * 128 + 2 * lane;
  h2v ha = u2h(hp[0]), hb = u2h(hp[1]);
  float h0f = (float)ha[0], h1f = (float)ha[1], h2f = (float)hb[0], h3f = (float)hb[1];
  float p0, p1, p2, p3;
  {
    const float* w0 = outW + 4 * lane;
    const float* w1 = outW + 256 + 4 * lane;
    const float* w2 = outW + 512 + 4 * lane;
    const float* w3 = outW + 768 + 4 * lane;
    p0 = h0f * w0[0] + h1f * w0[1] + h2f * w0[2] + h3f * w0[3];
    p1 = h0f * w1[0] + h1f * w1[1] + h2f * w1[2] + h3f * w1[3];
    p2 = h0f * w2[0] + h1f * w2[1] + h2f * w2[2] + h3f * w2[3];
    p3 = h0f * w3[0] + h1f * w3[1] + h2f * w3[2] + h3f * w3[3];
  }
#pragma unroll
  for (int off = 32; off > 0; off >>= 1) {
    p0 += __shfl_xor(p0, off, 64);
    p1 += __shfl_xor(p1, off, 64);
    p2 += __shfl_xor(p2, off, 64);
    p3 += __shfl_xor(p3, off, 64);
  }
  if (lane == 0) {
    float l0 = p0 + outB[0], l1 = p1 + outB[1], l2 = p2 + outB[2], l3 = p3 + outB[3];
    float mm = fmaxf(fmaxf(l0, l1), fmaxf(l2, l3));
    float s = __expf(l0 - mm) + __expf(l1 - mm) + __expf(l2 - mm) + __expf(l3 - mm);
    float lse = mm + __logf(s);
    float* o = out + (size_t)row * 4;
    o[0] = l0 - lse; o[1] = l1 - lse; o[2] = l2 - lse; o[3] = l3 - lse;
  }
}

// ---------------------------------------------------------------------------
// K6: labels (as float) and weights passthrough
// ---------------------------------------------------------------------------
__global__ void k_passthrough(const int* __restrict__ labels,
                              const float* __restrict__ weights,
                              float* __restrict__ out) {
  int i = blockIdx.x * blockDim.x + threadIdx.x;
  if (i < 40960) {
    out[164160 + i] = (float)labels[i];
    out[164160 + 40960 + i] = weights[i];
  }
}

// ---------------------------------------------------------------------------
extern "C" void kernel_launch(void* const* d_in, const int* in_sizes, int n_in,
                              void* d_out, int out_size, void* d_ws, size_t ws_size,
                              hipStream_t stream) {
  (void)in_sizes; (void)n_in; (void)out_size; (void)ws_size;
  const float* feat = (const float*)d_in[0];
  const float* score = (const float*)d_in[1];
  const float* box = (const float*)d_in[2];
  const float* orig = (const float*)d_in[3];
  const int* labels = (const int*)d_in[4];
  const float* weights = (const float*)d_in[5];
  const float* appear_W = (const float*)d_in[8];
  const float* appear_b = (const float*)d_in[9];
  const float* featlin_W = (const float*)d_in[10];
  const float* featlin_b = (const float*)d_in[11];
  const float* eWihF = (const float*)d_in[12];
  const float* eWhhF = (const float*)d_in[13];
  const float* ebihF = (const float*)d_in[14];
  const float* ebhhF = (const float*)d_in[15];
  const float* eWihB = (const float*)d_in[16];
  const float* eWhhB = (const float*)d_in[17];
  const float* ebihB = (const float*)d_in[18];
  const float* ebhhB = (const float*)d_in[19];
  const float* dec_emb = (const float*)d_in[20];
  const float* dWih = (const float*)d_in[21];
  const float* dWhh = (const float*)d_in[22];
  const float* dbih = (const float*)d_in[23];
  const float* dbhh = (const float*)d_in[24];
  const float* outW = (const float*)d_in[25];
  const float* outB = (const float*)d_in[26];
  float* out = (float*)d_out;

  char* ws = (char*)d_ws;
  float* allf = (float*)ws;                                     // 36.7MB; reused as wpack
  unsigned* encf2 = (unsigned*)(ws + (size_t)40960 * 224 * 4);  // 10.5MB
  float* dec_h0 = (float*)(ws + (size_t)40960 * 224 * 4 + (size_t)40960 * 64 * 4);
  float* dec_gi = dec_h0 + 80 * 256;                            // 80*4*768 f32
  unsigned* dhs2 = (unsigned*)(dec_gi + 80 * 4 * 768);          // 80*513*128 u32 = 21MB
  uint4* wpack = (uint4*)allf;                                  // 80*48*512*16B = 31.5MB

  k_fill_misc<<<15360, 256, 0, stream>>>(score, box, orig, allf);
  k_gemm_appear<<<640, 256, 0, stream>>>(feat, appear_W, appear_b, allf);
  k_gemm_featlin<<<640, 256, 0, stream>>>(allf, featlin_W, featlin_b, encf2);
  k_pack_dec<<<80 * 48, 512, 0, stream>>>(dWhh, wpack);
  k_dec_gi<<<80, 256, 0, stream>>>(dWih, dbih, dec_emb, dec_gi);
  k_enc_gru<<<160, 512, 0, stream>>>(encf2, eWihF, eWhhF, ebihF, ebhhF,
                                     eWihB, eWhhB, ebihB, ebhhB, dec_h0);
  k_dec_gru<<<80, 512, 0, stream>>>(wpack, dbhh, dec_gi, dec_h0, labels, dhs2);
  k_out<<<10260, 256, 0, stream>>>(dhs2, outW, outB, out);
  k_passthrough<<<160, 256, 0, stream>>>(labels, weights, out);
}

// Round 12
// 1557.434 us; speedup vs baseline: 1.1678x; 1.0244x over previous
//
#include <hip/hip_runtime.h>

// ---------------------------------------------------------------------------
// Encoder_Decoder v12 = v11 with the three-pipe weight split rebalanced using
// the measured VGPR headroom (v11: VGPR=104 of a 256 budget; LDS pipe was the
// critical path at ~2000cy/step from 19 LDS-resident chunks).
//   decoder: 24 reg chunks / 12 LDS / 12 streamed via PINNED slots (each slot
//            reloads its own chunk right after consumption -> full-step lead).
//   encoder: 16 reg chunks / 8 LDS (66KB -> 2 blocks/CU, 4 waves/SIMD).
// Structure otherwise identical to v11 (fused gates, 1 lgkm barrier/step,
// double-buffered h2s, deferred out-projection).
// ---------------------------------------------------------------------------

typedef __fp16 h2v __attribute__((ext_vector_type(2)));

__device__ __forceinline__ h2v pk2(float a, float b) {
  return __builtin_amdgcn_cvt_pkrtz(a, b);
}
__device__ __forceinline__ unsigned h2u(h2v h) { return __builtin_bit_cast(unsigned, h); }
__device__ __forceinline__ h2v u2h(unsigned u) { return __builtin_bit_cast(h2v, u); }
__device__ __forceinline__ float fdot2f(h2v a, h2v b, float c) {
  return __builtin_amdgcn_fdot2(a, b, c, false);
}
__device__ __forceinline__ float sigf(float x) { return 1.f / (1.f + __expf(-x)); }
__device__ __forceinline__ float tanhfast(float x) { return 2.f / (1.f + __expf(-2.f * x)) - 1.f; }

__device__ __forceinline__ uint4 pack8u(float4 a, float4 b) {
  uint4 o;
  o.x = h2u(pk2(a.x, a.y)); o.y = h2u(pk2(a.z, a.w));
  o.z = h2u(pk2(b.x, b.y)); o.w = h2u(pk2(b.z, b.w));
  return o;
}

__device__ __forceinline__ float dotu4(uint4 cv, h2v a0, h2v a1, h2v a2, h2v a3,
                                       float acc) {
  acc = fdot2f(u2h(cv.x), a0, acc);
  acc = fdot2f(u2h(cv.y), a1, acc);
  acc = fdot2f(u2h(cv.z), a2, acc);
  acc = fdot2f(u2h(cv.w), a3, acc);
  return acc;
}

template <int CTRL>
__device__ __forceinline__ float dppadd(float acc, float v) {
  int r = __builtin_amdgcn_update_dpp(0, __float_as_int(v), CTRL, 0xF, 0xF, true);
  return acc + __int_as_float(r);
}
__device__ __forceinline__ float swz4add(float acc, float v) {
  return acc + __int_as_float(__builtin_amdgcn_ds_swizzle(__float_as_int(v), 0x101F));
}

// 8 partials, slot k on lane holds row-id k^(m&7); returns row-id (m&7) sum.
__device__ __forceinline__ float reduce8s(float p0, float p1, float p2, float p3,
                                          float p4, float p5, float p6, float p7) {
  p0 = dppadd<0xB1>(p0, p1);
  p2 = dppadd<0xB1>(p2, p3);
  p4 = dppadd<0xB1>(p4, p5);
  p6 = dppadd<0xB1>(p6, p7);
  p0 = dppadd<0x4E>(p0, p2);
  p4 = dppadd<0x4E>(p4, p6);
  p0 = swz4add(p0, p4);
  p0 = dppadd<0x128>(p0, p0);
  return p0;
}

#define BAR_LGKM()                                     \
  asm volatile("s_waitcnt lgkmcnt(0)" ::: "memory");   \
  __builtin_amdgcn_s_barrier();                        \
  asm volatile("" ::: "memory");

// ---------------------------------------------------------------------------
// K0: fill allf[:,128:224]
// ---------------------------------------------------------------------------
__global__ void k_fill_misc(const float* __restrict__ score, const float* __restrict__ box,
                            const float* __restrict__ orig, float* __restrict__ allf) {
  int i = blockIdx.x * blockDim.x + threadIdx.x;
  if (i >= 40960 * 96) return;
  int row = i / 96, k = i - row * 96;
  float v;
  if (k == 0) v = score[row];
  else if (k < 5) v = box[row * 4 + (k - 1)];
  else v = orig[(size_t)row * 91 + (k - 5)];
  allf[(size_t)row * 224 + 128 + k] = v;
}

// ---------------------------------------------------------------------------
// K1: allf[:,0:128] = relu(feat @ appear_W^T + appear_b)
// ---------------------------------------------------------------------------
__global__ __launch_bounds__(256) void k_gemm_appear(
    const float* __restrict__ A, const float* __restrict__ W,
    const float* __restrict__ bias, float* __restrict__ allf) {
  __shared__ float As[32][68];
  __shared__ float Ws[32][132];
  const int tid = threadIdx.x;
  const int tx = tid & 15, ty = tid >> 4;
  const int r0 = blockIdx.x * 64;
  const int lr = tid >> 3;
  const int lk = (tid & 7) * 4;
  float acc[4][8];
#pragma unroll
  for (int i = 0; i < 4; ++i)
#pragma unroll
    for (int j = 0; j < 8; ++j) acc[i][j] = 0.f;

  for (int k0 = 0; k0 < 1024; k0 += 32) {
#pragma unroll
    for (int i = 0; i < 2; ++i) {
      int rr = lr + i * 32;
      float4 v = *(const float4*)(A + (size_t)(r0 + rr) * 1024 + k0 + lk);
      As[lk + 0][rr] = v.x; As[lk + 1][rr] = v.y; As[lk + 2][rr] = v.z; As[lk + 3][rr] = v.w;
    }
#pragma unroll
    for (int i = 0; i < 4; ++i) {
      int wr = lr + i * 32;
      float4 v = *(const float4*)(W + (size_t)wr * 1024 + k0 + lk);
      Ws[lk + 0][wr] = v.x; Ws[lk + 1][wr] = v.y; Ws[lk + 2][wr] = v.z; Ws[lk + 3][wr] = v.w;
    }
    __syncthreads();
#pragma unroll
    for (int kk = 0; kk < 32; ++kk) {
      float4 a = *(const float4*)&As[kk][ty * 4];
      float4 w0 = *(const float4*)&Ws[kk][tx * 8];
      float4 w1 = *(const float4*)&Ws[kk][tx * 8 + 4];
      float av[4] = {a.x, a.y, a.z, a.w};
      float wv[8] = {w0.x, w0.y, w0.z, w0.w, w1.x, w1.y, w1.z, w1.w};
#pragma unroll
      for (int i = 0; i < 4; ++i)
#pragma unroll
        for (int j = 0; j < 8; ++j) acc[i][j] = fmaf(av[i], wv[j], acc[i][j]);
    }
    __syncthreads();
  }
#pragma unroll
  for (int i = 0; i < 4; ++i) {
    int row = r0 + ty * 4 + i;
#pragma unroll
    for (int j = 0; j < 8; ++j) {
      int col = tx * 8 + j;
      float v = acc[i][j] + bias[col];
      allf[(size_t)row * 224 + col] = fmaxf(v, 0.f);
    }
  }
}

// ---------------------------------------------------------------------------
// K2: enc_feat = relu(allf @ featlin_W^T + b), stored packed f16x2
// ---------------------------------------------------------------------------
__global__ __launch_bounds__(256) void k_gemm_featlin(
    const float* __restrict__ A, const float* __restrict__ W,
    const float* __restrict__ bias, unsigned* __restrict__ encf2) {
  __shared__ float As[32][68];
  __shared__ float Ws[32][132];
  const int tid = threadIdx.x;
  const int tx = tid & 15, ty = tid >> 4;
  const int r0 = blockIdx.x * 64;
  const int lr = tid >> 3;
  const int lk = (tid & 7) * 4;
  float acc[4][8];
#pragma unroll
  for (int i = 0; i < 4; ++i)
#pragma unroll
    for (int j = 0; j < 8; ++j) acc[i][j] = 0.f;

  for (int k0 = 0; k0 < 224; k0 += 32) {
#pragma unroll
    for (int i = 0; i < 2; ++i) {
      int rr = lr + i * 32;
      float4 v = *(const float4*)(A + (size_t)(r0 + rr) * 224 + k0 + lk);
      As[lk + 0][rr] = v.x; As[lk + 1][rr] = v.y; As[lk + 2][rr] = v.z; As[lk + 3][rr] = v.w;
    }
#pragma unroll
    for (int i = 0; i < 4; ++i) {
      int wr = lr + i * 32;
      float4 v = *(const float4*)(W + (size_t)wr * 224 + k0 + lk);
      Ws[lk + 0][wr] = v.x; Ws[lk + 1][wr] = v.y; Ws[lk + 2][wr] = v.z; Ws[lk + 3][wr] = v.w;
    }
    __syncthreads();
#pragma unroll
    for (int kk = 0; kk < 32; ++kk) {
      float4 a = *(const float4*)&As[kk][ty * 4];
      float4 w0 = *(const float4*)&Ws[kk][tx * 8];
      float4 w1 = *(const float4*)&Ws[kk][tx * 8 + 4];
      float av[4] = {a.x, a.y, a.z, a.w};
      float wv[8] = {w0.x, w0.y, w0.z, w0.w, w1.x, w1.y, w1.z, w1.w};
#pragma unroll
      for (int i = 0; i < 4; ++i)
#pragma unroll
        for (int j = 0; j < 8; ++j) acc[i][j] = fmaf(av[i], wv[j], acc[i][j]);
    }
    __syncthreads();
  }
#pragma unroll
  for (int i = 0; i < 4; ++i) {
    int row = r0 + ty * 4 + i;
    unsigned* orow = encf2 + (size_t)row * 64;
#pragma unroll
    for (int p = 0; p < 4; ++p) {
      int col = tx * 8 + 2 * p;
      float a = fmaxf(acc[i][2 * p] + bias[col], 0.f);
      float b = fmaxf(acc[i][2 * p + 1] + bias[col + 1], 0.f);
      orow[tx * 4 + p] = h2u(pk2(a, b));
    }
  }
}

// ---------------------------------------------------------------------------
// K3: decoder input projections gi[c][v][r] (bih folded in)
// ---------------------------------------------------------------------------
__global__ __launch_bounds__(256) void k_dec_gi(
    const float* __restrict__ Wih, const float* __restrict__ bih,
    const float* __restrict__ emb, float* __restrict__ gi) {
  __shared__ float e[4][32];
  const int c = blockIdx.x, tid = threadIdx.x;
  if (tid < 128) e[tid >> 5][tid & 31] = emb[tid];
  __syncthreads();
#pragma unroll
  for (int i = 0; i < 3; ++i) {
    int r = tid + i * 256;
    const float* w = Wih + ((size_t)c * 768 + r) * 32;
    float b = bih[(size_t)c * 768 + r];
    float a0 = b, a1 = b, a2 = b, a3 = b;
#pragma unroll
    for (int k = 0; k < 32; ++k) {
      float wv = w[k];
      a0 = fmaf(wv, e[0][k], a0);
      a1 = fmaf(wv, e[1][k], a1);
      a2 = fmaf(wv, e[2][k], a2);
      a3 = fmaf(wv, e[3][k], a3);
    }
    gi[((size_t)c * 4 + 0) * 768 + r] = a0;
    gi[((size_t)c * 4 + 1) * 768 + r] = a1;
    gi[((size_t)c * 4 + 2) * 768 + r] = a2;
    gi[((size_t)c * 4 + 3) * 768 + r] = a3;
  }
}

// ---------------------------------------------------------------------------
// K3b: pack dec_Whh -> f16 chunks. ic = gt*16 + k*2 + hf. Thread (G,m,mw):
// row = gt*256 + 8G + (k^mw), cols 16m+8hf..+7.
// ---------------------------------------------------------------------------
__global__ __launch_bounds__(512) void k_pack_dec(
    const float* __restrict__ Whh, uint4* __restrict__ wpk) {
  const int c = blockIdx.x / 48, ic = blockIdx.x % 48;
  const int tid = threadIdx.x;
  const int G = tid >> 4, m = tid & 15, mw = m & 7;
  const int gt = ic >> 4, k = (ic & 15) >> 1, hf = ic & 1;
  const int row = gt * 256 + 8 * G + (k ^ mw);
  const float* src = Whh + ((size_t)c * 768 + row) * 256 + 16 * m + 8 * hf;
  wpk[((size_t)c * 48 + ic) * 512 + tid] =
      pack8u(*(const float4*)src, *(const float4*)(src + 4));
}

// ---------------------------------------------------------------------------
// K4: encoder GRU, fused gates, 1 barrier/step. 160 blocks x 512 threads.
// Chunks: r k0..7 + z k0..7 in regs (16 = 64 VGPR); n k0..7 in LDS (8 = 66KB
// total -> 2 blocks/CU, 4 waves/SIMD, 128-VGPR budget).
// ---------------------------------------------------------------------------
#define ELOAD(gt, k, DST)                                                          \
  {                                                                                \
    int rid_ = (k) ^ mw;                                                           \
    const float* Mx_ = ((k) & 1) ? baseB : baseA;                                  \
    const float4* ps_ =                                                            \
        (const float4*)(Mx_ + ((size_t)((gt) * 128 + 4 * G + (rid_ >> 1))) * 128 + \
                        8 * m);                                                    \
    DST = pack8u(ps_[0], ps_[1]);                                                  \
  }                                                                                \
  __builtin_amdgcn_sched_barrier(0);

__global__ __launch_bounds__(512) void k_enc_gru(
    const unsigned* __restrict__ encf2,
    const float* __restrict__ WihF, const float* __restrict__ WhhF,
    const float* __restrict__ bihF, const float* __restrict__ bhhF,
    const float* __restrict__ WihB, const float* __restrict__ WhhB,
    const float* __restrict__ bihB, const float* __restrict__ bhhB,
    float* __restrict__ dec_h0) {
  const int blk = blockIdx.x;
  const int c = blk >> 1, dir = blk & 1;
  const int tid = threadIdx.x;
  const int G = tid >> 4, m = tid & 15, mw = m & 7;

  const float* Wih = (dir ? WihB : WihF) + (size_t)c * 384 * 128;
  const float* Whh = (dir ? WhhB : WhhF) + (size_t)c * 384 * 128;
  const float* bih = (dir ? bihB : bihF) + (size_t)c * 384;
  const float* bhh = (dir ? bhhB : bhhF) + (size_t)c * 384;

  const float* baseA = (mw & 1) ? Whh : Wih;  // for even k
  const float* baseB = (mw & 1) ? Wih : Whh;  // for odd  k

  __shared__ __align__(16) unsigned x2s[2][64];
  __shared__ __align__(16) unsigned h2s[2][64];
  __shared__ __align__(16) uint4 wle[8 * 512];  // 65536 B -> 2 blocks/CU

  // reg chunks: r k0..7, z k0..7
  uint4 er0, er1, er2, er3, er4, er5, er6, er7;
  uint4 ez0, ez1, ez2, ez3, ez4, ez5, ez6, ez7;
  ELOAD(0, 0, er0) ELOAD(0, 1, er1) ELOAD(0, 2, er2) ELOAD(0, 3, er3)
  ELOAD(0, 4, er4) ELOAD(0, 5, er5) ELOAD(0, 6, er6) ELOAD(0, 7, er7)
  ELOAD(1, 0, ez0) ELOAD(1, 1, ez1) ELOAD(1, 2, ez2) ELOAD(1, 3, ez3)
  ELOAD(1, 4, ez4) ELOAD(1, 5, ez5) ELOAD(1, 6, ez6) ELOAD(1, 7, ez7)
  // LDS chunks: n k0..7 -> slots 0..7
  {
    uint4 t0;
    ELOAD(2, 0, t0) wle[0 * 512 + tid] = t0;
    ELOAD(2, 1, t0) wle[1 * 512 + tid] = t0;
    ELOAD(2, 2, t0) wle[2 * 512 + tid] = t0;
    ELOAD(2, 3, t0) wle[3 * 512 + tid] = t0;
    ELOAD(2, 4, t0) wle[4 * 512 + tid] = t0;
    ELOAD(2, 5, t0) wle[5 * 512 + tid] = t0;
    ELOAD(2, 6, t0) wle[6 * 512 + tid] = t0;
    ELOAD(2, 7, t0) wle[7 * 512 + tid] = t0;
  }

  const int u = 4 * G + (mw >> 1);
  const float brz_r = bih[u] + bhh[u];
  const float brz_z = bih[128 + u] + bhh[128 + u];
  const float b_in = bih[256 + u];
  const float b_hn = bhh[256 + u];

  if (tid < 64) h2s[0][tid] = 0u;
  if (tid >= 448) {
    int lane = tid - 448;
    x2s[0][lane] = (dir == 0) ? encf2[((size_t)c * 512 + 0) * 64 + lane] : 0x3C003C00u;
  }
  float hreg = 0.f;
  __syncthreads();

  const uint4* wl = wle + tid;

  for (int t = 0; t <= 512; ++t) {
    unsigned xpre = 0;
    if (tid >= 448 && t < 512) {
      int tn = t + 1, lane = tid - 448;
      int row = (dir == 0) ? ((tn < 512) ? tn : -1) : (512 - tn);
      xpre = (row < 0) ? 0x3C003C00u : encf2[((size_t)c * 512 + row) * 64 + lane];
    }
    uint4 xv = ((const uint4*)&x2s[t & 1][0])[m];
    uint4 hv = ((const uint4*)&h2s[t & 1][0])[m];
    h2v x0 = u2h(xv.x), x1 = u2h(xv.y), x2 = u2h(xv.z), x3 = u2h(xv.w);
    h2v hh0 = u2h(hv.x), hh1 = u2h(hv.y), hh2 = u2h(hv.z), hh3 = u2h(hv.w);
    bool oddl = (mw & 1);
    h2v a0 = oddl ? hh0 : x0, a1 = oddl ? hh1 : x1, a2 = oddl ? hh2 : x2, a3 = oddl ? hh3 : x3;
    h2v b0 = oddl ? x0 : hh0, b1 = oddl ? x1 : hh1, b2 = oddl ? x2 : hh2, b3 = oddl ? x3 : hh3;
#define EA(ch) dotu4(ch, a0, a1, a2, a3, 0.f)
#define EB(ch) dotu4(ch, b0, b1, b2, b3, 0.f)
    float vR = reduce8s(EA(er0), EB(er1), EA(er2), EB(er3),
                        EA(er4), EB(er5), EA(er6), EB(er7));
    float vZ = reduce8s(EA(ez0), EB(ez1), EA(ez2), EB(ez3),
                        EA(ez4), EB(ez5), EA(ez6), EB(ez7));
    float vN = reduce8s(EA(wl[0 * 512]), EB(wl[1 * 512]), EA(wl[2 * 512]), EB(wl[3 * 512]),
                        EA(wl[4 * 512]), EB(wl[5 * 512]), EA(wl[6 * 512]), EB(wl[7 * 512]));
#undef EA
#undef EB
    float oR = __shfl_xor(vR, 1, 64);
    float oZ = __shfl_xor(vZ, 1, 64);
    float oN = __shfl_xor(vN, 1, 64);
    float r = sigf(vR + oR + brz_r);
    float z = sigf(vZ + oZ + brz_z);
    float i_n = oddl ? oN : vN;
    float h_n = oddl ? vN : oN;
    float n = tanhfast(i_n + b_in + r * (h_n + b_hn));
    float hn = (1.f - z) * n + z * hreg;
    hreg = hn;
    float prt = __shfl_xor(hn, 2, 64);
    if (m < 8 && (mw & 3) == 0) h2s[(t + 1) & 1][2 * G + (mw >> 2)] = h2u(pk2(hn, prt));
    if (tid >= 448 && t < 512) x2s[(t + 1) & 1][tid - 448] = xpre;
    BAR_LGKM();
  }
  if ((m < 8) && ((mw & 1) == 0))
    dec_h0[(size_t)c * 256 + dir * 128 + u] = hreg;
}

// ---------------------------------------------------------------------------
// K5: decoder GRU, fused gates, 1 barrier/step, deferred out-proj.
// 80 blocks x 512 threads. Chunks ic0..23 regs (96 VGPR), ic24..35 LDS
// (98KB), ic36..47 streamed via PINNED slots (full-step reload lead).
// ---------------------------------------------------------------------------
#define CONSX(sa, sb) dotu4(sb, g4, g5, g6, g7, dotu4(sa, g0, g1, g2, g3, 0.f))

__global__ __launch_bounds__(512) void k_dec_gru(
    const uint4* __restrict__ wpk, const float* __restrict__ bhh,
    const float* __restrict__ gi, const float* __restrict__ h0,
    const int* __restrict__ labels, unsigned* __restrict__ dhs2) {
  const int c = blockIdx.x, tid = threadIdx.x;
  const int G = tid >> 4, m = tid & 15, mw = m & 7;

  __shared__ __align__(16) unsigned h2s[2][128];
  __shared__ int labs[513];
  __shared__ __align__(16) uint4 wlds[12 * 512];  // 98304 B

  const uint4* wp = wpk + (size_t)c * 48 * 512 + tid;
  const uint4* wpS = wp + 36 * 512;

  // LDS-resident chunks ic24..35
  for (int j = 0; j < 12; ++j) wlds[j * 512 + tid] = wp[(24 + j) * 512];
  __builtin_amdgcn_sched_barrier(0);
  // reg chunks ic0..23
  uint4 ra0 = wp[0 * 512], ra1 = wp[1 * 512], ra2 = wp[2 * 512], ra3 = wp[3 * 512];
  uint4 ra4 = wp[4 * 512], ra5 = wp[5 * 512], ra6 = wp[6 * 512], ra7 = wp[7 * 512];
  __builtin_amdgcn_sched_barrier(0);
  uint4 ra8 = wp[8 * 512], ra9 = wp[9 * 512], ra10 = wp[10 * 512], ra11 = wp[11 * 512];
  uint4 ra12 = wp[12 * 512], ra13 = wp[13 * 512], ra14 = wp[14 * 512], ra15 = wp[15 * 512];
  __builtin_amdgcn_sched_barrier(0);
  uint4 ra16 = wp[16 * 512], ra17 = wp[17 * 512], ra18 = wp[18 * 512], ra19 = wp[19 * 512];
  uint4 ra20 = wp[20 * 512], ra21 = wp[21 * 512], ra22 = wp[22 * 512], ra23 = wp[23 * 512];
  __builtin_amdgcn_sched_barrier(0);
  // pinned stream slots: ic36..47
  uint4 ss0 = wpS[0 * 512], ss1 = wpS[1 * 512], ss2 = wpS[2 * 512], ss3 = wpS[3 * 512];
  uint4 ss4 = wpS[4 * 512], ss5 = wpS[5 * 512], ss6 = wpS[6 * 512], ss7 = wpS[7 * 512];
  uint4 ss8 = wpS[8 * 512], ss9 = wpS[9 * 512], ss10 = wpS[10 * 512], ss11 = wpS[11 * 512];

  const int u = 8 * G + mw;
  const float bb0 = bhh[(size_t)c * 768 + u];
  const float bb1 = bhh[(size_t)c * 768 + 256 + u];
  const float bb2 = bhh[(size_t)c * 768 + 512 + u];
  const float* gib = gi + (size_t)c * 4 * 768;
  unsigned* dout = dhs2 + (size_t)c * 513 * 128 + 4 * G + (mw >> 1);

  if (tid < 512) labs[tid + 1] = labels[(size_t)c * 512 + tid];
  if (tid == 0) labs[0] = 2;  // SOS
  float hreg = h0[(size_t)c * 256 + u];
  {
    float oth = __shfl_xor(hreg, 1, 64);
    if (m < 8 && (mw & 1) == 0) h2s[0][4 * G + (mw >> 1)] = h2u(pk2(hreg, oth));
  }
  __syncthreads();

  const uint4* wl = wlds + tid;

  for (int t = 0; t <= 512; ++t) {
    uint4 ha = ((const uint4*)&h2s[t & 1][0])[2 * m];
    uint4 hb = ((const uint4*)&h2s[t & 1][0])[2 * m + 1];
    h2v g0 = u2h(ha.x), g1 = u2h(ha.y), g2 = u2h(ha.z), g3 = u2h(ha.w);
    h2v g4 = u2h(hb.x), g5 = u2h(hb.y), g6 = u2h(hb.z), g7 = u2h(hb.w);
    int sel = labs[t];
    const float* gp = gib + sel * 768;
    float giR = gp[u], giZ = gp[256 + u], giN = gp[512 + u];
    // --- r batch: ic0..15 (all regs)
    float p0 = CONSX(ra0, ra1), p1 = CONSX(ra2, ra3);
    float p2 = CONSX(ra4, ra5), p3 = CONSX(ra6, ra7);
    float p4 = CONSX(ra8, ra9), p5 = CONSX(ra10, ra11);
    float p6 = CONSX(ra12, ra13), p7 = CONSX(ra14, ra15);
    float rsum = reduce8s(p0, p1, p2, p3, p4, p5, p6, p7);
    // --- z batch: ic16..31 (regs 16..23 + LDS 24..31)
    p0 = CONSX(ra16, ra17); p1 = CONSX(ra18, ra19);
    p2 = CONSX(ra20, ra21); p3 = CONSX(ra22, ra23);
    p4 = CONSX(wl[0 * 512], wl[1 * 512]);
    p5 = CONSX(wl[2 * 512], wl[3 * 512]);
    p6 = CONSX(wl[4 * 512], wl[5 * 512]);
    p7 = CONSX(wl[6 * 512], wl[7 * 512]);
    float zsum = reduce8s(p0, p1, p2, p3, p4, p5, p6, p7);
    // --- n batch: ic32..35 (LDS) + ic36..47 (pinned stream, reload after use)
    p0 = CONSX(wl[8 * 512], wl[9 * 512]);
    p1 = CONSX(wl[10 * 512], wl[11 * 512]);
    p2 = CONSX(ss0, ss1); ss0 = wpS[0 * 512]; ss1 = wpS[1 * 512];
    p3 = CONSX(ss2, ss3); ss2 = wpS[2 * 512]; ss3 = wpS[3 * 512];
    p4 = CONSX(ss4, ss5); ss4 = wpS[4 * 512]; ss5 = wpS[5 * 512];
    p5 = CONSX(ss6, ss7); ss6 = wpS[6 * 512]; ss7 = wpS[7 * 512];
    p6 = CONSX(ss8, ss9); ss8 = wpS[8 * 512]; ss9 = wpS[9 * 512];
    p7 = CONSX(ss10, ss11); ss10 = wpS[10 * 512]; ss11 = wpS[11 * 512];
    float nsum = reduce8s(p0, p1, p2, p3, p4, p5, p6, p7);
    // --- fused gates (all on this lane)
    float r = sigf(giR + rsum + bb0);
    float z = sigf(giZ + zsum + bb1);
    float n = tanhfast(giN + r * (nsum + bb2));
    float hn = (1.f - z) * n + z * hreg;
    hreg = hn;
    float oth = __shfl_xor(hn, 1, 64);
    if (m < 8 && (mw & 1) == 0) {
      unsigned pk = h2u(pk2(hn, oth));
      h2s[(t + 1) & 1][4 * G + (mw >> 1)] = pk;
      dout[(size_t)t * 128] = pk;
    }
    BAR_LGKM();
  }
}

// ---------------------------------------------------------------------------
// K5b: out-projection + log_softmax over 41040 rows (1 wave/row).
// ---------------------------------------------------------------------------
__global__ __launch_bounds__(256) void k_out(
    const unsigned* __restrict__ dhs2, const float* __restrict__ outW,
    const float* __restrict__ outB, float* __restrict__ out) {
  int row = blockIdx.x * 4 + (threadIdx.x >> 6);
  if (row >= 41040) return;
  int lane = threadIdx.x & 63;
  const unsigned* hp = dhs2 + (size_t)row * 128 + 2 * lane;
  h2v ha = u2h(hp[0]), hb = u2h(hp[1]);
  float h0f = (float)ha[0], h1f = (float)ha[1], h2f = (float)hb[0], h3f = (float)hb[1];
  float p0, p1, p2, p3;
  {
    const float* w0 = outW + 4 * lane;
    const float* w1 = outW + 256 + 4 * lane;
    const float* w2 = outW + 512 + 4 * lane;
    const float* w3 = outW + 768 + 4 * lane;
    p0 = h0f * w0[0] + h1f * w0[1] + h2f * w0[2] + h3f * w0[3];
    p1 = h0f * w1[0] + h1f * w1[1] + h2f * w1[2] + h3f * w1[3];
    p2 = h0f * w2[0] + h1f * w2[1] + h2f * w2[2] + h3f * w2[3];
    p3 = h0f * w3[0] + h1f * w3[1] + h2f * w3[2] + h3f * w3[3];
  }
#pragma unroll
  for (int off = 32; off > 0; off >>= 1) {
    p0 += __shfl_xor(p0, off, 64);
    p1 += __shfl_xor(p1, off, 64);
    p2 += __shfl_xor(p2, off, 64);
    p3 += __shfl_xor(p3, off, 64);
  }
  if (lane == 0) {
    float l0 = p0 + outB[0], l1 = p1 + outB[1], l2 = p2 + outB[2], l3 = p3 + outB[3];
    float mm = fmaxf(fmaxf(l0, l1), fmaxf(l2, l3));
    float s = __expf(l0 - mm) + __expf(l1 - mm) + __expf(l2 - mm) + __expf(l3 - mm);
    float lse = mm + __logf(s);
    float* o = out + (size_t)row * 4;
    o[0] = l0 - lse; o[1] = l1 - lse; o[2] = l2 - lse; o[3] = l3 - lse;
  }
}

// ---------------------------------------------------------------------------
// K6: labels (as float) and weights passthrough
// ---------------------------------------------------------------------------
__global__ void k_passthrough(const int* __restrict__ labels,
                              const float* __restrict__ weights,
                              float* __restrict__ out) {
  int i = blockIdx.x * blockDim.x + threadIdx.x;
  if (i < 40960) {
    out[164160 + i] = (float)labels[i];
    out[164160 + 40960 + i] = weights[i];
  }
}

// ---------------------------------------------------------------------------
extern "C" void kernel_launch(void* const* d_in, const int* in_sizes, int n_in,
                              void* d_out, int out_size, void* d_ws, size_t ws_size,
                              hipStream_t stream) {
  (void)in_sizes; (void)n_in; (void)out_size; (void)ws_size;
  const float* feat = (const float*)d_in[0];
  const float* score = (const float*)d_in[1];
  const float* box = (const float*)d_in[2];
  const float* orig = (const float*)d_in[3];
  const int* labels = (const int*)d_in[4];
  const float* weights = (const float*)d_in[5];
  const float* appear_W = (const float*)d_in[8];
  const float* appear_b = (const float*)d_in[9];
  const float* featlin_W = (const float*)d_in[10];
  const float* featlin_b = (const float*)d_in[11];
  const float* eWihF = (const float*)d_in[12];
  const float* eWhhF = (const float*)d_in[13];
  const float* ebihF = (const float*)d_in[14];
  const float* ebhhF = (const float*)d_in[15];
  const float* eWihB = (const float*)d_in[16];
  const float* eWhhB = (const float*)d_in[17];
  const float* ebihB = (const float*)d_in[18];
  const float* ebhhB = (const float*)d_in[19];
  const float* dec_emb = (const float*)d_in[20];
  const float* dWih = (const float*)d_in[21];
  const float* dWhh = (const float*)d_in[22];
  const float* dbih = (const float*)d_in[23];
  const float* dbhh = (const float*)d_in[24];
  const float* outW = (const float*)d_in[25];
  const float* outB = (const float*)d_in[26];
  float* out = (float*)d_out;

  char* ws = (char*)d_ws;
  float* allf = (float*)ws;                                     // 36.7MB; reused as wpack
  unsigned* encf2 = (unsigned*)(ws + (size_t)40960 * 224 * 4);  // 10.5MB
  float* dec_h0 = (float*)(ws + (size_t)40960 * 224 * 4 + (size_t)40960 * 64 * 4);
  float* dec_gi = dec_h0 + 80 * 256;                            // 80*4*768 f32
  unsigned* dhs2 = (unsigned*)(dec_gi + 80 * 4 * 768);          // 80*513*128 u32 = 21MB
  uint4* wpack = (uint4*)allf;                                  // 80*48*512*16B = 31.5MB

  k_fill_misc<<<15360, 256, 0, stream>>>(score, box, orig, allf);
  k_gemm_appear<<<640, 256, 0, stream>>>(feat, appear_W, appear_b, allf);
  k_gemm_featlin<<<640, 256, 0, stream>>>(allf, featlin_W, featlin_b, encf2);
  k_pack_dec<<<80 * 48, 512, 0, stream>>>(dWhh, wpack);
  k_dec_gi<<<80, 256, 0, stream>>>(dWih, dbih, dec_emb, dec_gi);
  k_enc_gru<<<160, 512, 0, stream>>>(encf2, eWihF, eWhhF, ebihF, ebhhF,
                                     eWihB, eWhhB, ebihB, ebhhB, dec_h0);
  k_dec_gru<<<80, 512, 0, stream>>>(wpack, dbhh, dec_gi, dec_h0, labels, dhs2);
  k_out<<<10260, 256, 0, stream>>>(dhs2, outW, outB, out);
  k_passthrough<<<160, 256, 0, stream>>>(labels, weights, out);
}